// Round 4
// baseline (3486.604 us; speedup 1.0000x reference)
//
#include <hip/hip_runtime.h>
#include <cstdint>

#define T_LEN 128
#define DA    16
#define DZ    32
#define HH    128

__device__ __forceinline__ float sigm(float x){ return 1.0f/(1.0f + __expf(-x)); }
__device__ __forceinline__ float tanh_f(float x){ return 1.0f - 2.0f/(__expf(2.0f*x)+1.0f); }
__device__ __forceinline__ float dot4(float4 a, float4 b){ return a.x*b.x + a.y*b.y + a.z*b.z + a.w*b.w; }

// ws layout (fp32 words):
//   [0,8192)         WihT0: float4 idx (k4*512+g), k4<4  -> Wih0[g][4*k4+kk]
//   [8192,73728)     WhhT0: k4<32
//   [73728,139264)   WihT1: k4<32
//   [139264,204800)  WhhT1: k4<32
//   [204800,205312)  b0 = bih0+bhh0
//   [205312,205824)  b1 = bih1+bhh1
//   [205824,402432)  alpha (512,128,3)

__global__ void prep_kernel(const float* __restrict__ Wih0, const float* __restrict__ Whh0,
                            const float* __restrict__ bih0, const float* __restrict__ bhh0,
                            const float* __restrict__ Wih1, const float* __restrict__ Whh1,
                            const float* __restrict__ bih1, const float* __restrict__ bhh1,
                            float* __restrict__ ws) {
  int idx = blockIdx.x*256 + threadIdx.x;
  if (idx < 8192) {
    int k4 = idx >> 11, g = (idx >> 2) & 511, kk = idx & 3;
    ws[idx] = Wih0[g*DA + k4*4 + kk];
  } else if (idx < 73728) {
    int f = idx - 8192;
    int k4 = f >> 11, g = (f >> 2) & 511, kk = f & 3;
    ws[idx] = Whh0[g*HH + k4*4 + kk];
  } else if (idx < 139264) {
    int f = idx - 73728;
    int k4 = f >> 11, g = (f >> 2) & 511, kk = f & 3;
    ws[idx] = Wih1[g*HH + k4*4 + kk];
  } else if (idx < 204800) {
    int f = idx - 139264;
    int k4 = f >> 11, g = (f >> 2) & 511, kk = f & 3;
    ws[idx] = Whh1[g*HH + k4*4 + kk];
  } else if (idx < 205312) {
    int j = idx - 204800;
    ws[idx] = bih0[j] + bhh0[j];
  } else if (idx < 205824) {
    int j = idx - 205312;
    ws[idx] = bih1[j] + bhh1[j];
  }
}

// Persistent 2-layer LSTM + softmax head, fp32 weights.
// 128 blocks x 512 threads x 4 batch rows: weight L2 traffic halves vs 2-row
// (13 GB, ~380 us L2 floor) and VALU floor on 128 CUs is ~341 us -> balanced.
// Thread = one gate (512 gates); h read via wave-uniform LDS broadcast.
__global__ __launch_bounds__(512) void lstm_kernel(
    const float* __restrict__ a, const float* __restrict__ a0,
    const float* __restrict__ ws, const float* __restrict__ Wlin,
    const float* __restrict__ blin, float* __restrict__ alpha_out) {
  const float4* Wih0p = (const float4*)(ws);
  const float4* Whh0p = (const float4*)(ws + 8192);
  const float4* Wih1p = (const float4*)(ws + 73728);
  const float4* Whh1p = (const float4*)(ws + 139264);
  const float* b0v = ws + 204800;
  const float* b1v = ws + 205312;

  __shared__ __align__(16) float sx[4][T_LEN][DA];
  __shared__ __align__(16) float sh0[4][HH];
  __shared__ __align__(16) float sh1[4][HH];
  __shared__ float sc0[4][HH], sc1[4][HH];
  __shared__ float gates[4][4*HH];
  __shared__ float sWl[3][HH];
  __shared__ float partial[8][3];

  int tid = threadIdx.x;
  int bb = blockIdx.x * 4;
  for (int i = tid; i < 4*T_LEN*DA; i += 512) {
    int r = i / (T_LEN*DA), rem = i % (T_LEN*DA), t = rem / DA, d = rem % DA;
    sx[r][t][d] = (t == 0) ? a0[d] : a[((size_t)(bb + r)*T_LEN + (t-1))*DA + d];
  }
  for (int i = tid; i < 3*HH; i += 512) sWl[i/HH][i%HH] = Wlin[i];
  if (tid < 4*HH) { int r = tid>>7, j = tid&127; sh0[r][j]=0.f; sc0[r][j]=0.f; sh1[r][j]=0.f; sc1[r][j]=0.f; }
  float bi0 = b0v[tid];
  float bi1 = b1v[tid];
  __syncthreads();

  #pragma unroll 1
  for (int t = 0; t < T_LEN; ++t) {
    // ---- layer 0: gate g=tid, batch rows 0..3 ----
    float g0 = bi0, g1 = bi0, g2 = bi0, g3 = bi0;
    #pragma unroll
    for (int k4 = 0; k4 < 4; ++k4) {
      float4 w = Wih0p[k4*512 + tid];
      float4 x0 = *(const float4*)&sx[0][t][4*k4];
      float4 x1 = *(const float4*)&sx[1][t][4*k4];
      float4 x2 = *(const float4*)&sx[2][t][4*k4];
      float4 x3 = *(const float4*)&sx[3][t][4*k4];
      g0 += dot4(w,x0); g1 += dot4(w,x1); g2 += dot4(w,x2); g3 += dot4(w,x3);
    }
    #pragma unroll 8
    for (int k4 = 0; k4 < 32; ++k4) {
      float4 w = Whh0p[k4*512 + tid];
      float4 h0 = *(const float4*)&sh0[0][4*k4];
      float4 h1 = *(const float4*)&sh0[1][4*k4];
      float4 h2 = *(const float4*)&sh0[2][4*k4];
      float4 h3 = *(const float4*)&sh0[3][4*k4];
      g0 += dot4(w,h0); g1 += dot4(w,h1); g2 += dot4(w,h2); g3 += dot4(w,h3);
    }
    gates[0][tid]=g0; gates[1][tid]=g1; gates[2][tid]=g2; gates[3][tid]=g3;
    __syncthreads();
    {
      int r = tid>>7, j = tid&127;
      float ig = gates[r][j], fg = gates[r][j+HH], gg = gates[r][j+2*HH], og = gates[r][j+3*HH];
      float c = sigm(fg)*sc0[r][j] + sigm(ig)*tanh_f(gg);
      sc0[r][j] = c;
      sh0[r][j] = sigm(og)*tanh_f(c);
    }
    __syncthreads();
    // ---- layer 1 ----
    g0 = bi1; g1 = bi1; g2 = bi1; g3 = bi1;
    #pragma unroll 8
    for (int k4 = 0; k4 < 32; ++k4) {
      float4 w = Wih1p[k4*512 + tid];
      float4 h0 = *(const float4*)&sh0[0][4*k4];
      float4 h1 = *(const float4*)&sh0[1][4*k4];
      float4 h2 = *(const float4*)&sh0[2][4*k4];
      float4 h3 = *(const float4*)&sh0[3][4*k4];
      g0 += dot4(w,h0); g1 += dot4(w,h1); g2 += dot4(w,h2); g3 += dot4(w,h3);
    }
    #pragma unroll 8
    for (int k4 = 0; k4 < 32; ++k4) {
      float4 w = Whh1p[k4*512 + tid];
      float4 h0 = *(const float4*)&sh1[0][4*k4];
      float4 h1 = *(const float4*)&sh1[1][4*k4];
      float4 h2 = *(const float4*)&sh1[2][4*k4];
      float4 h3 = *(const float4*)&sh1[3][4*k4];
      g0 += dot4(w,h0); g1 += dot4(w,h1); g2 += dot4(w,h2); g3 += dot4(w,h3);
    }
    gates[0][tid]=g0; gates[1][tid]=g1; gates[2][tid]=g2; gates[3][tid]=g3;
    __syncthreads();
    {
      int r = tid>>7, j = tid&127;
      float ig = gates[r][j], fg = gates[r][j+HH], gg = gates[r][j+2*HH], og = gates[r][j+3*HH];
      float c = sigm(fg)*sc1[r][j] + sigm(ig)*tanh_f(gg);
      sc1[r][j] = c;
      sh1[r][j] = sigm(og)*tanh_f(c);
    }
    __syncthreads();
    // ---- alpha = softmax(h1 @ Wlin^T + blin), 8 waves = 4 rows x 2 halves ----
    {
      int wv = tid>>6, lane = tid&63, r = wv>>1, jo = (wv&1)*64;
      float hv = sh1[r][jo+lane];
      float p0 = hv*sWl[0][jo+lane], p1 = hv*sWl[1][jo+lane], p2 = hv*sWl[2][jo+lane];
      #pragma unroll
      for (int off = 32; off > 0; off >>= 1) {
        p0 += __shfl_down(p0, off); p1 += __shfl_down(p1, off); p2 += __shfl_down(p2, off);
      }
      if (lane == 0) { partial[wv][0]=p0; partial[wv][1]=p1; partial[wv][2]=p2; }
    }
    __syncthreads();
    if (tid < 4) {
      float l0 = partial[2*tid][0]+partial[2*tid+1][0]+blin[0];
      float l1 = partial[2*tid][1]+partial[2*tid+1][1]+blin[1];
      float l2 = partial[2*tid][2]+partial[2*tid+1][2]+blin[2];
      float m = fmaxf(l0, fmaxf(l1, l2));
      float e0=__expf(l0-m), e1=__expf(l1-m), e2=__expf(l2-m);
      float inv = 1.0f/(e0+e1+e2);
      float* dst = alpha_out + (((size_t)(bb+tid))*T_LEN + t)*3;
      dst[0]=e0*inv; dst[1]=e1*inv; dst[2]=e2*inv;
    }
    __syncthreads();
  }
}

// Kalman scan v3: 256 threads/chain; Gauss-Jordan runs wave-synchronously in
// wave 0 (Aug in registers, shuffle broadcasts) -> 8 barriers/step instead of 41.
__global__ __launch_bounds__(256) void kalman_kernel(
    const float* __restrict__ a, const float* __restrict__ A,
    const float* __restrict__ C, const float* __restrict__ alpha,
    float* __restrict__ out) {
  __shared__ __align__(16) float Sg[DZ][36];    // Sigma_pred (kept symmetric)
  __shared__ __align__(16) float Am[DZ][36];    // A_next mix
  __shared__ __align__(16) float Cm[DA][36];    // C mix
  __shared__ __align__(16) float Nn[DZ][20];    // N = Sigma_pred @ C^T
  __shared__ __align__(16) float NnT[DA][36];   // N^T
  __shared__ __align__(16) float Aug[DA][36];   // [S | I] -> right half becomes Sinv
  __shared__ __align__(16) float Kg[DZ][20];    // Kalman gain
  __shared__ __align__(16) float Sp2[DZ][36];   // Sigma'
  __shared__ __align__(16) float T2m[DZ][36];   // A @ Sigma'
  __shared__ __align__(16) float sa[T_LEN][DA]; // observations for this chain
  __shared__ float salpha[T_LEN*3];
  __shared__ float muv[DZ], mun[DZ], rv[DA];

  int tid = threadIdx.x;
  int b = blockIdx.x;

  for (int e = tid; e < T_LEN*DA; e += 256) (&sa[0][0])[e] = a[(size_t)b*T_LEN*DA + e];
  for (int e = tid; e < T_LEN*3; e += 256) salpha[e] = alpha[(size_t)b*T_LEN*3 + e];
  for (int e = tid; e < DZ*36; e += 256) (&Sg[0][0])[e] = 0.0f;
  __syncthreads();
  if (tid < DZ) { Sg[tid][tid] = 1.0f; muv[tid] = 0.0f; }
  __syncthreads();

  const int i8 = tid >> 3, j4 = (tid & 7) * 4;     // 32x8 grid, 4-col tiles
  const int jA = tid & 7, jB = jA + 8;             // 32x16 via two cols
  const int i16 = tid >> 4, j16 = tid & 15;        // 16x16 grid

  #pragma unroll 1
  for (int t = 0; t < T_LEN; ++t) {
    int ta = (t < T_LEN-1) ? t+1 : t;
    float b10 = salpha[ta*3+0], b11 = salpha[ta*3+1], b12 = salpha[ta*3+2];
    float b00 = salpha[t*3+0],  b01 = salpha[t*3+1],  b02 = salpha[t*3+2];

    // ---- MIX: A_next (alpha[t+1]) and C_mix (alpha[t]) ----
    {
      const float4* A0 = (const float4*)(A + (size_t)(0*T_LEN + ta)*DZ*DZ);
      const float4* A1 = (const float4*)(A + (size_t)(1*T_LEN + ta)*DZ*DZ);
      const float4* A2 = (const float4*)(A + (size_t)(2*T_LEN + ta)*DZ*DZ);
      float4 v0 = A0[tid], v1 = A1[tid], v2 = A2[tid];
      float4 v;
      v.x = b10*v0.x + b11*v1.x + b12*v2.x;
      v.y = b10*v0.y + b11*v1.y + b12*v2.y;
      v.z = b10*v0.z + b11*v1.z + b12*v2.z;
      v.w = b10*v0.w + b11*v1.w + b12*v2.w;
      *(float4*)&Am[i8][j4] = v;
      if (tid < 128) {
        const float4* C0 = (const float4*)(C + (size_t)(0*T_LEN + t)*DA*DZ);
        const float4* C1 = (const float4*)(C + (size_t)(1*T_LEN + t)*DA*DZ);
        const float4* C2 = (const float4*)(C + (size_t)(2*T_LEN + t)*DA*DZ);
        float4 c0 = C0[tid], c1 = C1[tid], c2 = C2[tid];
        float4 c;
        c.x = b00*c0.x + b01*c1.x + b02*c2.x;
        c.y = b00*c0.y + b01*c1.y + b02*c2.y;
        c.z = b00*c0.z + b01*c1.z + b02*c2.z;
        c.w = b00*c0.w + b01*c1.w + b02*c2.w;
        *(float4*)&Cm[tid>>3][(tid&7)*4] = c;
      }
    }
    __syncthreads();

    // ---- N = Sigma_pred @ C^T (via Sigma symmetry); r = a_t - C @ mu_pred ----
    {
      float accA = 0.0f, accB = 0.0f;
      #pragma unroll
      for (int k4 = 0; k4 < 8; ++k4) {
        float4 s  = *(const float4*)&Sg[i8][k4*4];
        float4 cA = *(const float4*)&Cm[jA][k4*4];
        float4 cB = *(const float4*)&Cm[jB][k4*4];
        accA += dot4(s,cA); accB += dot4(s,cB);
      }
      Nn[i8][jA] = accA; Nn[i8][jB] = accB;
      NnT[jA][i8] = accA; NnT[jB][i8] = accB;
      if (tid < DA) {
        float acc = sa[t][tid];
        #pragma unroll
        for (int k = 0; k < DZ; ++k) acc -= Cm[tid][k]*muv[k];
        rv[tid] = acc;
      }
    }
    __syncthreads();

    // ---- Aug = [S | I],  S = C @ N + 0.01 I ----
    {
      float acc = 0.0f;
      #pragma unroll
      for (int k4 = 0; k4 < 8; ++k4) {
        float4 c = *(const float4*)&Cm[i16][k4*4];
        float4 n = *(const float4*)&NnT[j16][k4*4];
        acc += dot4(c,n);
      }
      Aug[i16][j16] = acc + ((i16 == j16) ? 0.01f : 0.0f);
      Aug[i16][16 + j16] = (i16 == j16) ? 1.0f : 0.0f;
    }
    __syncthreads();

    // ---- wave-synchronous Gauss-Jordan in wave 0 (S SPD, no pivoting) ----
    if (tid < 64) {
      int lane = tid;
      int r = lane >> 2, cb = lane & 3;          // row, 8-col block
      float v[8];
      #pragma unroll
      for (int j = 0; j < 8; ++j) v[j] = Aug[r][cb*8 + j];
      #pragma unroll
      for (int p = 0; p < DA; ++p) {
        float App = __shfl(v[p & 7], (p << 2) | (p >> 3), 64);
        float f   = __shfl(v[p & 7], (lane & 60) | (p >> 3), 64);
        float prow[8];
        #pragma unroll
        for (int j = 0; j < 8; ++j) prow[j] = __shfl(v[j], (p << 2) | cb, 64);
        float pinv = 1.0f / App;
        if (r == p) {
          #pragma unroll
          for (int j = 0; j < 8; ++j) v[j] *= pinv;
        } else {
          float fp = f * pinv;
          #pragma unroll
          for (int j = 0; j < 8; ++j) v[j] -= fp * prow[j];
        }
      }
      if (cb >= 2) {
        #pragma unroll
        for (int j = 0; j < 8; ++j) Aug[r][cb*8 + j] = v[j];
      }
    }
    __syncthreads();

    // ---- Kg = N @ Sinv (via Sinv symmetry: row j of right half) ----
    {
      float accA = 0.0f, accB = 0.0f;
      #pragma unroll
      for (int k4 = 0; k4 < 4; ++k4) {
        float4 n  = *(const float4*)&Nn[i8][k4*4];
        float4 sA = *(const float4*)&Aug[jA][16 + k4*4];
        float4 sB = *(const float4*)&Aug[jB][16 + k4*4];
        accA += dot4(n,sA); accB += dot4(n,sB);
      }
      Kg[i8][jA] = accA; Kg[i8][jB] = accB;
    }
    __syncthreads();

    // ---- mu = mu_pred + Kg r (write output); Sigma' = Sigma_pred - Kg N^T ----
    if (tid < DZ) {
      float m = muv[tid];
      #pragma unroll
      for (int k = 0; k < DA; ++k) m += Kg[tid][k]*rv[k];
      mun[tid] = m;
      out[((size_t)b*T_LEN + t)*DZ + tid] = m;
    }
    {
      float4 acc = *(const float4*)&Sg[i8][j4];
      #pragma unroll
      for (int k4 = 0; k4 < 4; ++k4) {
        float4 kg = *(const float4*)&Kg[i8][k4*4];
        float4 n0 = *(const float4*)&Nn[j4+0][k4*4];
        float4 n1 = *(const float4*)&Nn[j4+1][k4*4];
        float4 n2 = *(const float4*)&Nn[j4+2][k4*4];
        float4 n3 = *(const float4*)&Nn[j4+3][k4*4];
        acc.x -= dot4(kg,n0); acc.y -= dot4(kg,n1);
        acc.z -= dot4(kg,n2); acc.w -= dot4(kg,n3);
      }
      *(float4*)&Sp2[i8][j4] = acc;
    }
    __syncthreads();

    // ---- T2 = A_next @ Sigma' (via Sigma' symmetry) ----
    {
      float4 acc = make_float4(0.f,0.f,0.f,0.f);
      #pragma unroll
      for (int k4 = 0; k4 < 8; ++k4) {
        float4 am = *(const float4*)&Am[i8][k4*4];
        float4 s0 = *(const float4*)&Sp2[j4+0][k4*4];
        float4 s1 = *(const float4*)&Sp2[j4+1][k4*4];
        float4 s2 = *(const float4*)&Sp2[j4+2][k4*4];
        float4 s3 = *(const float4*)&Sp2[j4+3][k4*4];
        acc.x += dot4(am,s0); acc.y += dot4(am,s1);
        acc.z += dot4(am,s2); acc.w += dot4(am,s3);
      }
      *(float4*)&T2m[i8][j4] = acc;
    }
    __syncthreads();

    // ---- Sigma_next = T2 @ A_next^T + 0.01 I ; mu_next = A_next @ mu ----
    {
      float4 acc = make_float4(0.f,0.f,0.f,0.f);
      #pragma unroll
      for (int k4 = 0; k4 < 8; ++k4) {
        float4 t2 = *(const float4*)&T2m[i8][k4*4];
        float4 a0 = *(const float4*)&Am[j4+0][k4*4];
        float4 a1 = *(const float4*)&Am[j4+1][k4*4];
        float4 a2 = *(const float4*)&Am[j4+2][k4*4];
        float4 a3 = *(const float4*)&Am[j4+3][k4*4];
        acc.x += dot4(t2,a0); acc.y += dot4(t2,a1);
        acc.z += dot4(t2,a2); acc.w += dot4(t2,a3);
      }
      int d = i8 - j4;
      if (d >= 0 && d < 4) (&acc.x)[d] += 0.01f;
      *(float4*)&Sg[i8][j4] = acc;
    }
    if (tid < DZ) {
      float m = 0.0f;
      #pragma unroll
      for (int k = 0; k < DZ; ++k) m += Am[tid][k]*mun[k];
      muv[tid] = m;
    }
    __syncthreads();
  }
}

extern "C" void kernel_launch(void* const* d_in, const int* in_sizes, int n_in,
                              void* d_out, int out_size, void* d_ws, size_t ws_size,
                              hipStream_t stream) {
  const float* a    = (const float*)d_in[0];
  const float* A    = (const float*)d_in[1];
  const float* C    = (const float*)d_in[2];
  const float* a0   = (const float*)d_in[3];
  const float* Wih0 = (const float*)d_in[4];
  const float* Whh0 = (const float*)d_in[5];
  const float* bih0 = (const float*)d_in[6];
  const float* bhh0 = (const float*)d_in[7];
  const float* Wih1 = (const float*)d_in[8];
  const float* Whh1 = (const float*)d_in[9];
  const float* bih1 = (const float*)d_in[10];
  const float* bhh1 = (const float*)d_in[11];
  const float* Wlin = (const float*)d_in[12];
  const float* blin = (const float*)d_in[13];
  float* ws = (float*)d_ws;
  float* alpha = ws + 205824;
  float* out = (float*)d_out;

  prep_kernel<<<804, 256, 0, stream>>>(Wih0, Whh0, bih0, bhh0, Wih1, Whh1, bih1, bhh1, ws);
  lstm_kernel<<<128, 512, 0, stream>>>(a, a0, ws, Wlin, blin, alpha);
  kalman_kernel<<<512, 256, 0, stream>>>(a, A, C, alpha, out);
}

// Round 5
// 2601.511 us; speedup vs baseline: 1.3402x; 1.3402x over previous
//
#include <hip/hip_runtime.h>
#include <cstdint>

#define T_LEN 128
#define DA    16
#define DZ    32
#define HH    128

__device__ __forceinline__ float sigm(float x){ return 1.0f/(1.0f + __expf(-x)); }
__device__ __forceinline__ float tanh_f(float x){ return 1.0f - 2.0f/(__expf(2.0f*x)+1.0f); }
__device__ __forceinline__ float dot4(float4 a, float4 b){ return a.x*b.x + a.y*b.y + a.z*b.z + a.w*b.w; }

// ws layout (fp32 words):
//   [0,8192)         WihT0: float4 idx (k4*512+g), k4<4  -> Wih0[g][4*k4+kk]
//   [8192,73728)     WhhT0: k4<32
//   [73728,139264)   WihT1: k4<32
//   [139264,204800)  WhhT1: k4<32
//   [204800,205312)  b0 = bih0+bhh0
//   [205312,205824)  b1 = bih1+bhh1
//   [205824,402432)  alpha (512,128,3)

__global__ void prep_kernel(const float* __restrict__ Wih0, const float* __restrict__ Whh0,
                            const float* __restrict__ bih0, const float* __restrict__ bhh0,
                            const float* __restrict__ Wih1, const float* __restrict__ Whh1,
                            const float* __restrict__ bih1, const float* __restrict__ bhh1,
                            float* __restrict__ ws) {
  int idx = blockIdx.x*256 + threadIdx.x;
  if (idx < 8192) {
    int k4 = idx >> 11, g = (idx >> 2) & 511, kk = idx & 3;
    ws[idx] = Wih0[g*DA + k4*4 + kk];
  } else if (idx < 73728) {
    int f = idx - 8192;
    int k4 = f >> 11, g = (f >> 2) & 511, kk = f & 3;
    ws[idx] = Whh0[g*HH + k4*4 + kk];
  } else if (idx < 139264) {
    int f = idx - 73728;
    int k4 = f >> 11, g = (f >> 2) & 511, kk = f & 3;
    ws[idx] = Wih1[g*HH + k4*4 + kk];
  } else if (idx < 204800) {
    int f = idx - 139264;
    int k4 = f >> 11, g = (f >> 2) & 511, kk = f & 3;
    ws[idx] = Whh1[g*HH + k4*4 + kk];
  } else if (idx < 205312) {
    int j = idx - 204800;
    ws[idx] = bih0[j] + bhh0[j];
  } else if (idx < 205824) {
    int j = idx - 205312;
    ws[idx] = bih1[j] + bhh1[j];
  }
}

// Persistent 2-layer LSTM + softmax head, fp32 weights.
// 256 blocks x 512 threads x 2 rows: all 256 CUs active AND 2 waves/SIMD
// (round-4 showed 2 waves/SIMD gives 1.54x per-CU row-throughput; round-4's
// mistake was using only 128 CUs). Thread = one gate, 2 row-accumulators.
__global__ __launch_bounds__(512, 2) void lstm_kernel(
    const float* __restrict__ a, const float* __restrict__ a0,
    const float* __restrict__ ws, const float* __restrict__ Wlin,
    const float* __restrict__ blin, float* __restrict__ alpha_out) {
  const float4* Wih0p = (const float4*)(ws);
  const float4* Whh0p = (const float4*)(ws + 8192);
  const float4* Wih1p = (const float4*)(ws + 73728);
  const float4* Whh1p = (const float4*)(ws + 139264);
  const float* b0v = ws + 204800;
  const float* b1v = ws + 205312;

  __shared__ __align__(16) float sx[2][T_LEN][DA];
  __shared__ __align__(16) float sh0[2][HH];
  __shared__ __align__(16) float sh1[2][HH];
  __shared__ float sc0[2][HH], sc1[2][HH];
  __shared__ float gates[2][4*HH];
  __shared__ float sWl[3][HH];
  __shared__ float partial[4][3];

  int tid = threadIdx.x;
  int bb = blockIdx.x * 2;
  for (int i = tid; i < 2*T_LEN*DA; i += 512) {
    int r = i / (T_LEN*DA), rem = i % (T_LEN*DA), t = rem / DA, d = rem % DA;
    sx[r][t][d] = (t == 0) ? a0[d] : a[((size_t)(bb + r)*T_LEN + (t-1))*DA + d];
  }
  for (int i = tid; i < 3*HH; i += 512) sWl[i/HH][i%HH] = Wlin[i];
  if (tid < 2*HH) { int r = tid>>7, j = tid&127; sh0[r][j]=0.f; sc0[r][j]=0.f; sh1[r][j]=0.f; sc1[r][j]=0.f; }
  float bi0 = b0v[tid];
  float bi1 = b1v[tid];
  __syncthreads();

  #pragma unroll 1
  for (int t = 0; t < T_LEN; ++t) {
    // ---- layer 0: gate g=tid, batch rows 0..1 ----
    float g0 = bi0, g1 = bi0;
    #pragma unroll
    for (int k4 = 0; k4 < 4; ++k4) {
      float4 w = Wih0p[k4*512 + tid];
      float4 x0 = *(const float4*)&sx[0][t][4*k4];
      float4 x1 = *(const float4*)&sx[1][t][4*k4];
      g0 += dot4(w,x0); g1 += dot4(w,x1);
    }
    #pragma unroll 16
    for (int k4 = 0; k4 < 32; ++k4) {
      float4 w = Whh0p[k4*512 + tid];
      float4 h0 = *(const float4*)&sh0[0][4*k4];
      float4 h1 = *(const float4*)&sh0[1][4*k4];
      g0 += dot4(w,h0); g1 += dot4(w,h1);
    }
    gates[0][tid]=g0; gates[1][tid]=g1;
    __syncthreads();
    if (tid < 2*HH) {
      int r = tid>>7, j = tid&127;
      float ig = gates[r][j], fg = gates[r][j+HH], gg = gates[r][j+2*HH], og = gates[r][j+3*HH];
      float c = sigm(fg)*sc0[r][j] + sigm(ig)*tanh_f(gg);
      sc0[r][j] = c;
      sh0[r][j] = sigm(og)*tanh_f(c);
    }
    __syncthreads();
    // ---- layer 1 ----
    g0 = bi1; g1 = bi1;
    #pragma unroll 16
    for (int k4 = 0; k4 < 32; ++k4) {
      float4 w = Wih1p[k4*512 + tid];
      float4 h0 = *(const float4*)&sh0[0][4*k4];
      float4 h1 = *(const float4*)&sh0[1][4*k4];
      g0 += dot4(w,h0); g1 += dot4(w,h1);
    }
    #pragma unroll 16
    for (int k4 = 0; k4 < 32; ++k4) {
      float4 w = Whh1p[k4*512 + tid];
      float4 h0 = *(const float4*)&sh1[0][4*k4];
      float4 h1 = *(const float4*)&sh1[1][4*k4];
      g0 += dot4(w,h0); g1 += dot4(w,h1);
    }
    gates[0][tid]=g0; gates[1][tid]=g1;
    __syncthreads();
    if (tid < 2*HH) {
      int r = tid>>7, j = tid&127;
      float ig = gates[r][j], fg = gates[r][j+HH], gg = gates[r][j+2*HH], og = gates[r][j+3*HH];
      float c = sigm(fg)*sc1[r][j] + sigm(ig)*tanh_f(gg);
      sc1[r][j] = c;
      sh1[r][j] = sigm(og)*tanh_f(c);
    }
    __syncthreads();
    // ---- alpha = softmax(h1 @ Wlin^T + blin): 4 waves = 2 rows x 2 halves ----
    if (tid < 256) {
      int wv = tid>>6, lane = tid&63, r = wv>>1, jo = (wv&1)*64;
      float hv = sh1[r][jo+lane];
      float p0 = hv*sWl[0][jo+lane], p1 = hv*sWl[1][jo+lane], p2 = hv*sWl[2][jo+lane];
      #pragma unroll
      for (int off = 32; off > 0; off >>= 1) {
        p0 += __shfl_down(p0, off); p1 += __shfl_down(p1, off); p2 += __shfl_down(p2, off);
      }
      if (lane == 0) { partial[wv][0]=p0; partial[wv][1]=p1; partial[wv][2]=p2; }
    }
    __syncthreads();
    if (tid < 2) {
      float l0 = partial[2*tid][0]+partial[2*tid+1][0]+blin[0];
      float l1 = partial[2*tid][1]+partial[2*tid+1][1]+blin[1];
      float l2 = partial[2*tid][2]+partial[2*tid+1][2]+blin[2];
      float m = fmaxf(l0, fmaxf(l1, l2));
      float e0=__expf(l0-m), e1=__expf(l1-m), e2=__expf(l2-m);
      float inv = 1.0f/(e0+e1+e2);
      float* dst = alpha_out + (((size_t)(bb+tid))*T_LEN + t)*3;
      dst[0]=e0*inv; dst[1]=e1*inv; dst[2]=e2*inv;
    }
    __syncthreads();
  }
}

// Kalman scan v3: 256 threads/chain; Gauss-Jordan runs wave-synchronously in
// wave 0 (Aug in registers, shuffle broadcasts) -> 8 barriers/step instead of 41.
__global__ __launch_bounds__(256) void kalman_kernel(
    const float* __restrict__ a, const float* __restrict__ A,
    const float* __restrict__ C, const float* __restrict__ alpha,
    float* __restrict__ out) {
  __shared__ __align__(16) float Sg[DZ][36];    // Sigma_pred (kept symmetric)
  __shared__ __align__(16) float Am[DZ][36];    // A_next mix
  __shared__ __align__(16) float Cm[DA][36];    // C mix
  __shared__ __align__(16) float Nn[DZ][20];    // N = Sigma_pred @ C^T
  __shared__ __align__(16) float NnT[DA][36];   // N^T
  __shared__ __align__(16) float Aug[DA][36];   // [S | I] -> right half becomes Sinv
  __shared__ __align__(16) float Kg[DZ][20];    // Kalman gain
  __shared__ __align__(16) float Sp2[DZ][36];   // Sigma'
  __shared__ __align__(16) float T2m[DZ][36];   // A @ Sigma'
  __shared__ __align__(16) float sa[T_LEN][DA]; // observations for this chain
  __shared__ float salpha[T_LEN*3];
  __shared__ float muv[DZ], mun[DZ], rv[DA];

  int tid = threadIdx.x;
  int b = blockIdx.x;

  for (int e = tid; e < T_LEN*DA; e += 256) (&sa[0][0])[e] = a[(size_t)b*T_LEN*DA + e];
  for (int e = tid; e < T_LEN*3; e += 256) salpha[e] = alpha[(size_t)b*T_LEN*3 + e];
  for (int e = tid; e < DZ*36; e += 256) (&Sg[0][0])[e] = 0.0f;
  __syncthreads();
  if (tid < DZ) { Sg[tid][tid] = 1.0f; muv[tid] = 0.0f; }
  __syncthreads();

  const int i8 = tid >> 3, j4 = (tid & 7) * 4;     // 32x8 grid, 4-col tiles
  const int jA = tid & 7, jB = jA + 8;             // 32x16 via two cols
  const int i16 = tid >> 4, j16 = tid & 15;        // 16x16 grid

  #pragma unroll 1
  for (int t = 0; t < T_LEN; ++t) {
    int ta = (t < T_LEN-1) ? t+1 : t;
    float b10 = salpha[ta*3+0], b11 = salpha[ta*3+1], b12 = salpha[ta*3+2];
    float b00 = salpha[t*3+0],  b01 = salpha[t*3+1],  b02 = salpha[t*3+2];

    // ---- MIX: A_next (alpha[t+1]) and C_mix (alpha[t]) ----
    {
      const float4* A0 = (const float4*)(A + (size_t)(0*T_LEN + ta)*DZ*DZ);
      const float4* A1 = (const float4*)(A + (size_t)(1*T_LEN + ta)*DZ*DZ);
      const float4* A2 = (const float4*)(A + (size_t)(2*T_LEN + ta)*DZ*DZ);
      float4 v0 = A0[tid], v1 = A1[tid], v2 = A2[tid];
      float4 v;
      v.x = b10*v0.x + b11*v1.x + b12*v2.x;
      v.y = b10*v0.y + b11*v1.y + b12*v2.y;
      v.z = b10*v0.z + b11*v1.z + b12*v2.z;
      v.w = b10*v0.w + b11*v1.w + b12*v2.w;
      *(float4*)&Am[i8][j4] = v;
      if (tid < 128) {
        const float4* C0 = (const float4*)(C + (size_t)(0*T_LEN + t)*DA*DZ);
        const float4* C1 = (const float4*)(C + (size_t)(1*T_LEN + t)*DA*DZ);
        const float4* C2 = (const float4*)(C + (size_t)(2*T_LEN + t)*DA*DZ);
        float4 c0 = C0[tid], c1 = C1[tid], c2 = C2[tid];
        float4 c;
        c.x = b00*c0.x + b01*c1.x + b02*c2.x;
        c.y = b00*c0.y + b01*c1.y + b02*c2.y;
        c.z = b00*c0.z + b01*c1.z + b02*c2.z;
        c.w = b00*c0.w + b01*c1.w + b02*c2.w;
        *(float4*)&Cm[tid>>3][(tid&7)*4] = c;
      }
    }
    __syncthreads();

    // ---- N = Sigma_pred @ C^T (via Sigma symmetry); r = a_t - C @ mu_pred ----
    {
      float accA = 0.0f, accB = 0.0f;
      #pragma unroll
      for (int k4 = 0; k4 < 8; ++k4) {
        float4 s  = *(const float4*)&Sg[i8][k4*4];
        float4 cA = *(const float4*)&Cm[jA][k4*4];
        float4 cB = *(const float4*)&Cm[jB][k4*4];
        accA += dot4(s,cA); accB += dot4(s,cB);
      }
      Nn[i8][jA] = accA; Nn[i8][jB] = accB;
      NnT[jA][i8] = accA; NnT[jB][i8] = accB;
      if (tid < DA) {
        float acc = sa[t][tid];
        #pragma unroll
        for (int k = 0; k < DZ; ++k) acc -= Cm[tid][k]*muv[k];
        rv[tid] = acc;
      }
    }
    __syncthreads();

    // ---- Aug = [S | I],  S = C @ N + 0.01 I ----
    {
      float acc = 0.0f;
      #pragma unroll
      for (int k4 = 0; k4 < 8; ++k4) {
        float4 c = *(const float4*)&Cm[i16][k4*4];
        float4 n = *(const float4*)&NnT[j16][k4*4];
        acc += dot4(c,n);
      }
      Aug[i16][j16] = acc + ((i16 == j16) ? 0.01f : 0.0f);
      Aug[i16][16 + j16] = (i16 == j16) ? 1.0f : 0.0f;
    }
    __syncthreads();

    // ---- wave-synchronous Gauss-Jordan in wave 0 (S SPD, no pivoting) ----
    if (tid < 64) {
      int lane = tid;
      int r = lane >> 2, cb = lane & 3;          // row, 8-col block
      float v[8];
      #pragma unroll
      for (int j = 0; j < 8; ++j) v[j] = Aug[r][cb*8 + j];
      #pragma unroll
      for (int p = 0; p < DA; ++p) {
        float App = __shfl(v[p & 7], (p << 2) | (p >> 3), 64);
        float f   = __shfl(v[p & 7], (lane & 60) | (p >> 3), 64);
        float prow[8];
        #pragma unroll
        for (int j = 0; j < 8; ++j) prow[j] = __shfl(v[j], (p << 2) | cb, 64);
        float pinv = 1.0f / App;
        if (r == p) {
          #pragma unroll
          for (int j = 0; j < 8; ++j) v[j] *= pinv;
        } else {
          float fp = f * pinv;
          #pragma unroll
          for (int j = 0; j < 8; ++j) v[j] -= fp * prow[j];
        }
      }
      if (cb >= 2) {
        #pragma unroll
        for (int j = 0; j < 8; ++j) Aug[r][cb*8 + j] = v[j];
      }
    }
    __syncthreads();

    // ---- Kg = N @ Sinv (via Sinv symmetry: row j of right half) ----
    {
      float accA = 0.0f, accB = 0.0f;
      #pragma unroll
      for (int k4 = 0; k4 < 4; ++k4) {
        float4 n  = *(const float4*)&Nn[i8][k4*4];
        float4 sA = *(const float4*)&Aug[jA][16 + k4*4];
        float4 sB = *(const float4*)&Aug[jB][16 + k4*4];
        accA += dot4(n,sA); accB += dot4(n,sB);
      }
      Kg[i8][jA] = accA; Kg[i8][jB] = accB;
    }
    __syncthreads();

    // ---- mu = mu_pred + Kg r (write output); Sigma' = Sigma_pred - Kg N^T ----
    if (tid < DZ) {
      float m = muv[tid];
      #pragma unroll
      for (int k = 0; k < DA; ++k) m += Kg[tid][k]*rv[k];
      mun[tid] = m;
      out[((size_t)b*T_LEN + t)*DZ + tid] = m;
    }
    {
      float4 acc = *(const float4*)&Sg[i8][j4];
      #pragma unroll
      for (int k4 = 0; k4 < 4; ++k4) {
        float4 kg = *(const float4*)&Kg[i8][k4*4];
        float4 n0 = *(const float4*)&Nn[j4+0][k4*4];
        float4 n1 = *(const float4*)&Nn[j4+1][k4*4];
        float4 n2 = *(const float4*)&Nn[j4+2][k4*4];
        float4 n3 = *(const float4*)&Nn[j4+3][k4*4];
        acc.x -= dot4(kg,n0); acc.y -= dot4(kg,n1);
        acc.z -= dot4(kg,n2); acc.w -= dot4(kg,n3);
      }
      *(float4*)&Sp2[i8][j4] = acc;
    }
    __syncthreads();

    // ---- T2 = A_next @ Sigma' (via Sigma' symmetry) ----
    {
      float4 acc = make_float4(0.f,0.f,0.f,0.f);
      #pragma unroll
      for (int k4 = 0; k4 < 8; ++k4) {
        float4 am = *(const float4*)&Am[i8][k4*4];
        float4 s0 = *(const float4*)&Sp2[j4+0][k4*4];
        float4 s1 = *(const float4*)&Sp2[j4+1][k4*4];
        float4 s2 = *(const float4*)&Sp2[j4+2][k4*4];
        float4 s3 = *(const float4*)&Sp2[j4+3][k4*4];
        acc.x += dot4(am,s0); acc.y += dot4(am,s1);
        acc.z += dot4(am,s2); acc.w += dot4(am,s3);
      }
      *(float4*)&T2m[i8][j4] = acc;
    }
    __syncthreads();

    // ---- Sigma_next = T2 @ A_next^T + 0.01 I ; mu_next = A_next @ mu ----
    {
      float4 acc = make_float4(0.f,0.f,0.f,0.f);
      #pragma unroll
      for (int k4 = 0; k4 < 8; ++k4) {
        float4 t2 = *(const float4*)&T2m[i8][k4*4];
        float4 a0 = *(const float4*)&Am[j4+0][k4*4];
        float4 a1 = *(const float4*)&Am[j4+1][k4*4];
        float4 a2 = *(const float4*)&Am[j4+2][k4*4];
        float4 a3 = *(const float4*)&Am[j4+3][k4*4];
        acc.x += dot4(t2,a0); acc.y += dot4(t2,a1);
        acc.z += dot4(t2,a2); acc.w += dot4(t2,a3);
      }
      int d = i8 - j4;
      if (d >= 0 && d < 4) (&acc.x)[d] += 0.01f;
      *(float4*)&Sg[i8][j4] = acc;
    }
    if (tid < DZ) {
      float m = 0.0f;
      #pragma unroll
      for (int k = 0; k < DZ; ++k) m += Am[tid][k]*mun[k];
      muv[tid] = m;
    }
    __syncthreads();
  }
}

extern "C" void kernel_launch(void* const* d_in, const int* in_sizes, int n_in,
                              void* d_out, int out_size, void* d_ws, size_t ws_size,
                              hipStream_t stream) {
  const float* a    = (const float*)d_in[0];
  const float* A    = (const float*)d_in[1];
  const float* C    = (const float*)d_in[2];
  const float* a0   = (const float*)d_in[3];
  const float* Wih0 = (const float*)d_in[4];
  const float* Whh0 = (const float*)d_in[5];
  const float* bih0 = (const float*)d_in[6];
  const float* bhh0 = (const float*)d_in[7];
  const float* Wih1 = (const float*)d_in[8];
  const float* Whh1 = (const float*)d_in[9];
  const float* bih1 = (const float*)d_in[10];
  const float* bhh1 = (const float*)d_in[11];
  const float* Wlin = (const float*)d_in[12];
  const float* blin = (const float*)d_in[13];
  float* ws = (float*)d_ws;
  float* alpha = ws + 205824;
  float* out = (float*)d_out;

  prep_kernel<<<804, 256, 0, stream>>>(Wih0, Whh0, bih0, bhh0, Wih1, Whh1, bih1, bhh1, ws);
  lstm_kernel<<<256, 512, 0, stream>>>(a, a0, ws, Wlin, blin, alpha);
  kalman_kernel<<<512, 256, 0, stream>>>(a, A, C, alpha, out);
}

// Round 6
// 1605.384 us; speedup vs baseline: 2.1718x; 1.6205x over previous
//
#include <hip/hip_runtime.h>
#include <hip/hip_fp16.h>
#include <cstdint>

#define T_LEN 128
#define DA    16
#define DZ    32
#define HH    128

__device__ __forceinline__ float sigm(float x){ return 1.0f/(1.0f + __expf(-x)); }
__device__ __forceinline__ float tanh_f(float x){ return 1.0f - 2.0f/(__expf(2.0f*x)+1.0f); }
__device__ __forceinline__ float dot4(float4 a, float4 b){ return a.x*b.x + a.y*b.y + a.z*b.z + a.w*b.w; }

typedef _Float16 h2v __attribute__((ext_vector_type(2)));
__device__ __forceinline__ float fdot2(uint32_t w, uint32_t h, float acc){
  union{uint32_t u; h2v v;} a, b; a.u = w; b.u = h;
  return __builtin_amdgcn_fdot2(a.v, b.v, acc, false);
}
__device__ __forceinline__ uint32_t packh2(float x, float y){
  return (uint32_t)__half_as_ushort(__float2half(x)) |
         ((uint32_t)__half_as_ushort(__float2half(y)) << 16);
}

// ws layout (32-bit words):
//   [0,4096)         Wih0h fp16-pairs: word idx (m*512+g)*4+q, m<2, q<4 -> w[g][8m+2q..+1]
//   [4096,36864)     Whh0h: m<16
//   [36864,69632)    Wih1h: m<16
//   [69632,102400)   Whh1h: m<16
//   [102400,102912)  b0 = bih0+bhh0 (f32)
//   [102912,103424)  b1 = bih1+bhh1 (f32)
//   [103424,300032)  alpha (512,128,3) f32

__global__ void prep_kernel(const float* __restrict__ Wih0, const float* __restrict__ Whh0,
                            const float* __restrict__ bih0, const float* __restrict__ bhh0,
                            const float* __restrict__ Wih1, const float* __restrict__ Whh1,
                            const float* __restrict__ bih1, const float* __restrict__ bhh1,
                            uint32_t* __restrict__ ws) {
  int idx = blockIdx.x*256 + threadIdx.x;
  if (idx < 4096) {
    int q = idx & 3, g = (idx >> 2) & 511, m = idx >> 11;
    int k0 = 8*m + 2*q;
    ws[idx] = packh2(Wih0[g*DA + k0], Wih0[g*DA + k0 + 1]);
  } else if (idx < 36864) {
    int f = idx - 4096;
    int q = f & 3, g = (f >> 2) & 511, m = f >> 11;
    int k0 = 8*m + 2*q;
    ws[idx] = packh2(Whh0[g*HH + k0], Whh0[g*HH + k0 + 1]);
  } else if (idx < 69632) {
    int f = idx - 36864;
    int q = f & 3, g = (f >> 2) & 511, m = f >> 11;
    int k0 = 8*m + 2*q;
    ws[idx] = packh2(Wih1[g*HH + k0], Wih1[g*HH + k0 + 1]);
  } else if (idx < 102400) {
    int f = idx - 69632;
    int q = f & 3, g = (f >> 2) & 511, m = f >> 11;
    int k0 = 8*m + 2*q;
    ws[idx] = packh2(Whh1[g*HH + k0], Whh1[g*HH + k0 + 1]);
  } else if (idx < 102912) {
    int j = idx - 102400;
    ((float*)ws)[idx] = bih0[j] + bhh0[j];
  } else if (idx < 103424) {
    int j = idx - 102912;
    ((float*)ws)[idx] = bih1[j] + bhh1[j];
  }
}

// Persistent 2-layer LSTM + softmax head. fp16 weights via v_dot2_f32_f16
// (fp32 accumulate): 50 uint4 loads + 400 fdot2 per thread per step (halved
// from fp32's 100 loads / 800 FMA). 256 blocks x 512 threads x 2 rows.
__global__ __launch_bounds__(512, 2) void lstm_kernel(
    const float* __restrict__ a, const float* __restrict__ a0,
    const uint32_t* __restrict__ wsw, const float* __restrict__ Wlin,
    const float* __restrict__ blin, float* __restrict__ alpha_out) {
  const uint4* Wih0p = (const uint4*)(wsw);           // m*512+g, m<2
  const uint4* Whh0p = (const uint4*)(wsw + 4096);    // m<16
  const uint4* Wih1p = (const uint4*)(wsw + 36864);   // m<16
  const uint4* Whh1p = (const uint4*)(wsw + 69632);   // m<16
  const float* b0v = (const float*)(wsw + 102400);
  const float* b1v = (const float*)(wsw + 102912);

  __shared__ __align__(16) uint32_t sxh[2][T_LEN][8];  // x packed half2
  __shared__ __align__(16) uint32_t sh0h[2][64];       // h0 packed half2
  __shared__ __align__(16) uint32_t sh1h[2][64];       // h1 packed half2
  __shared__ float sh1f[2][HH];                        // h1 fp32 (softmax head)
  __shared__ float sc0[2][HH], sc1[2][HH];
  __shared__ float gates[2][4*HH];
  __shared__ float sWl[3][HH];
  __shared__ float partial[4][3];

  int tid = threadIdx.x;
  int bb = blockIdx.x * 2;
  for (int i = tid; i < 2*T_LEN*8; i += 512) {
    int r = i / (T_LEN*8), rem = i % (T_LEN*8), t = rem >> 3, p = rem & 7;
    float x0, x1;
    if (t == 0) { x0 = a0[2*p]; x1 = a0[2*p+1]; }
    else {
      const float* src = a + ((size_t)(bb + r)*T_LEN + (t-1))*DA;
      x0 = src[2*p]; x1 = src[2*p+1];
    }
    sxh[r][t][p] = packh2(x0, x1);
  }
  for (int i = tid; i < 3*HH; i += 512) sWl[i/HH][i%HH] = Wlin[i];
  if (tid < 128) { int r = tid>>6, p = tid&63; sh0h[r][p] = 0u; sh1h[r][p] = 0u; }
  if (tid < 256) { int r = tid>>7, j = tid&127; sc0[r][j] = 0.f; sc1[r][j] = 0.f; }
  float bi0 = b0v[tid];
  float bi1 = b1v[tid];
  __syncthreads();

  #pragma unroll 1
  for (int t = 0; t < T_LEN; ++t) {
    // ---- layer 0: gate g=tid, rows 0..1 ----
    float g0 = bi0, g1 = bi0;
    #pragma unroll
    for (int m = 0; m < 2; ++m) {
      uint4 w = Wih0p[m*512 + tid];
      uint4 x0 = *(const uint4*)&sxh[0][t][4*m];
      uint4 x1 = *(const uint4*)&sxh[1][t][4*m];
      g0 = fdot2(w.x, x0.x, g0); g0 = fdot2(w.y, x0.y, g0);
      g0 = fdot2(w.z, x0.z, g0); g0 = fdot2(w.w, x0.w, g0);
      g1 = fdot2(w.x, x1.x, g1); g1 = fdot2(w.y, x1.y, g1);
      g1 = fdot2(w.z, x1.z, g1); g1 = fdot2(w.w, x1.w, g1);
    }
    #pragma unroll 8
    for (int m = 0; m < 16; ++m) {
      uint4 w = Whh0p[m*512 + tid];
      uint4 h0 = *(const uint4*)&sh0h[0][4*m];
      uint4 h1 = *(const uint4*)&sh0h[1][4*m];
      g0 = fdot2(w.x, h0.x, g0); g0 = fdot2(w.y, h0.y, g0);
      g0 = fdot2(w.z, h0.z, g0); g0 = fdot2(w.w, h0.w, g0);
      g1 = fdot2(w.x, h1.x, g1); g1 = fdot2(w.y, h1.y, g1);
      g1 = fdot2(w.z, h1.z, g1); g1 = fdot2(w.w, h1.w, g1);
    }
    gates[0][tid] = g0; gates[1][tid] = g1;
    __syncthreads();
    if (tid < 128) {
      int r = tid>>6, p = tid&63, j0 = 2*p, j1 = j0 + 1;
      float i0 = gates[r][j0],     f0 = gates[r][j0+HH],
            q0 = gates[r][j0+2*HH], o0 = gates[r][j0+3*HH];
      float c0 = sigm(f0)*sc0[r][j0] + sigm(i0)*tanh_f(q0);
      sc0[r][j0] = c0;
      float hv0 = sigm(o0)*tanh_f(c0);
      float i1 = gates[r][j1],     f1 = gates[r][j1+HH],
            q1 = gates[r][j1+2*HH], o1 = gates[r][j1+3*HH];
      float c1 = sigm(f1)*sc0[r][j1] + sigm(i1)*tanh_f(q1);
      sc0[r][j1] = c1;
      float hv1 = sigm(o1)*tanh_f(c1);
      sh0h[r][p] = packh2(hv0, hv1);
    }
    __syncthreads();
    // ---- layer 1 ----
    g0 = bi1; g1 = bi1;
    #pragma unroll 8
    for (int m = 0; m < 16; ++m) {
      uint4 w = Wih1p[m*512 + tid];
      uint4 h0 = *(const uint4*)&sh0h[0][4*m];
      uint4 h1 = *(const uint4*)&sh0h[1][4*m];
      g0 = fdot2(w.x, h0.x, g0); g0 = fdot2(w.y, h0.y, g0);
      g0 = fdot2(w.z, h0.z, g0); g0 = fdot2(w.w, h0.w, g0);
      g1 = fdot2(w.x, h1.x, g1); g1 = fdot2(w.y, h1.y, g1);
      g1 = fdot2(w.z, h1.z, g1); g1 = fdot2(w.w, h1.w, g1);
    }
    #pragma unroll 8
    for (int m = 0; m < 16; ++m) {
      uint4 w = Whh1p[m*512 + tid];
      uint4 h0 = *(const uint4*)&sh1h[0][4*m];
      uint4 h1 = *(const uint4*)&sh1h[1][4*m];
      g0 = fdot2(w.x, h0.x, g0); g0 = fdot2(w.y, h0.y, g0);
      g0 = fdot2(w.z, h0.z, g0); g0 = fdot2(w.w, h0.w, g0);
      g1 = fdot2(w.x, h1.x, g1); g1 = fdot2(w.y, h1.y, g1);
      g1 = fdot2(w.z, h1.z, g1); g1 = fdot2(w.w, h1.w, g1);
    }
    gates[0][tid] = g0; gates[1][tid] = g1;
    __syncthreads();
    if (tid < 128) {
      int r = tid>>6, p = tid&63, j0 = 2*p, j1 = j0 + 1;
      float i0 = gates[r][j0],     f0 = gates[r][j0+HH],
            q0 = gates[r][j0+2*HH], o0 = gates[r][j0+3*HH];
      float c0 = sigm(f0)*sc1[r][j0] + sigm(i0)*tanh_f(q0);
      sc1[r][j0] = c0;
      float hv0 = sigm(o0)*tanh_f(c0);
      float i1 = gates[r][j1],     f1 = gates[r][j1+HH],
            q1 = gates[r][j1+2*HH], o1 = gates[r][j1+3*HH];
      float c1 = sigm(f1)*sc1[r][j1] + sigm(i1)*tanh_f(q1);
      sc1[r][j1] = c1;
      float hv1 = sigm(o1)*tanh_f(c1);
      sh1h[r][p] = packh2(hv0, hv1);
      sh1f[r][j0] = hv0; sh1f[r][j1] = hv1;
    }
    __syncthreads();
    // ---- alpha = softmax(h1 @ Wlin^T + blin): 4 waves = 2 rows x 2 halves ----
    if (tid < 256) {
      int wv = tid>>6, lane = tid&63, r = wv>>1, jo = (wv&1)*64;
      float hv = sh1f[r][jo+lane];
      float p0 = hv*sWl[0][jo+lane], p1 = hv*sWl[1][jo+lane], p2 = hv*sWl[2][jo+lane];
      #pragma unroll
      for (int off = 32; off > 0; off >>= 1) {
        p0 += __shfl_down(p0, off); p1 += __shfl_down(p1, off); p2 += __shfl_down(p2, off);
      }
      if (lane == 0) { partial[wv][0]=p0; partial[wv][1]=p1; partial[wv][2]=p2; }
    }
    __syncthreads();
    if (tid < 2) {
      float l0 = partial[2*tid][0]+partial[2*tid+1][0]+blin[0];
      float l1 = partial[2*tid][1]+partial[2*tid+1][1]+blin[1];
      float l2 = partial[2*tid][2]+partial[2*tid+1][2]+blin[2];
      float m = fmaxf(l0, fmaxf(l1, l2));
      float e0=__expf(l0-m), e1=__expf(l1-m), e2=__expf(l2-m);
      float inv = 1.0f/(e0+e1+e2);
      float* dst = alpha_out + (((size_t)(bb+tid))*T_LEN + t)*3;
      dst[0]=e0*inv; dst[1]=e1*inv; dst[2]=e2*inv;
    }
    __syncthreads();
  }
}

// Kalman scan v3 (unchanged from round 5): 256 threads/chain; wave-synchronous
// Gauss-Jordan in wave 0; symmetry-based row-major matmuls.
__global__ __launch_bounds__(256) void kalman_kernel(
    const float* __restrict__ a, const float* __restrict__ A,
    const float* __restrict__ C, const float* __restrict__ alpha,
    float* __restrict__ out) {
  __shared__ __align__(16) float Sg[DZ][36];
  __shared__ __align__(16) float Am[DZ][36];
  __shared__ __align__(16) float Cm[DA][36];
  __shared__ __align__(16) float Nn[DZ][20];
  __shared__ __align__(16) float NnT[DA][36];
  __shared__ __align__(16) float Aug[DA][36];
  __shared__ __align__(16) float Kg[DZ][20];
  __shared__ __align__(16) float Sp2[DZ][36];
  __shared__ __align__(16) float T2m[DZ][36];
  __shared__ __align__(16) float sa[T_LEN][DA];
  __shared__ float salpha[T_LEN*3];
  __shared__ float muv[DZ], mun[DZ], rv[DA];

  int tid = threadIdx.x;
  int b = blockIdx.x;

  for (int e = tid; e < T_LEN*DA; e += 256) (&sa[0][0])[e] = a[(size_t)b*T_LEN*DA + e];
  for (int e = tid; e < T_LEN*3; e += 256) salpha[e] = alpha[(size_t)b*T_LEN*3 + e];
  for (int e = tid; e < DZ*36; e += 256) (&Sg[0][0])[e] = 0.0f;
  __syncthreads();
  if (tid < DZ) { Sg[tid][tid] = 1.0f; muv[tid] = 0.0f; }
  __syncthreads();

  const int i8 = tid >> 3, j4 = (tid & 7) * 4;
  const int jA = tid & 7, jB = jA + 8;
  const int i16 = tid >> 4, j16 = tid & 15;

  #pragma unroll 1
  for (int t = 0; t < T_LEN; ++t) {
    int ta = (t < T_LEN-1) ? t+1 : t;
    float b10 = salpha[ta*3+0], b11 = salpha[ta*3+1], b12 = salpha[ta*3+2];
    float b00 = salpha[t*3+0],  b01 = salpha[t*3+1],  b02 = salpha[t*3+2];

    {
      const float4* A0 = (const float4*)(A + (size_t)(0*T_LEN + ta)*DZ*DZ);
      const float4* A1 = (const float4*)(A + (size_t)(1*T_LEN + ta)*DZ*DZ);
      const float4* A2 = (const float4*)(A + (size_t)(2*T_LEN + ta)*DZ*DZ);
      float4 v0 = A0[tid], v1 = A1[tid], v2 = A2[tid];
      float4 v;
      v.x = b10*v0.x + b11*v1.x + b12*v2.x;
      v.y = b10*v0.y + b11*v1.y + b12*v2.y;
      v.z = b10*v0.z + b11*v1.z + b12*v2.z;
      v.w = b10*v0.w + b11*v1.w + b12*v2.w;
      *(float4*)&Am[i8][j4] = v;
      if (tid < 128) {
        const float4* C0 = (const float4*)(C + (size_t)(0*T_LEN + t)*DA*DZ);
        const float4* C1 = (const float4*)(C + (size_t)(1*T_LEN + t)*DA*DZ);
        const float4* C2 = (const float4*)(C + (size_t)(2*T_LEN + t)*DA*DZ);
        float4 c0 = C0[tid], c1 = C1[tid], c2 = C2[tid];
        float4 c;
        c.x = b00*c0.x + b01*c1.x + b02*c2.x;
        c.y = b00*c0.y + b01*c1.y + b02*c2.y;
        c.z = b00*c0.z + b01*c1.z + b02*c2.z;
        c.w = b00*c0.w + b01*c1.w + b02*c2.w;
        *(float4*)&Cm[tid>>3][(tid&7)*4] = c;
      }
    }
    __syncthreads();

    {
      float accA = 0.0f, accB = 0.0f;
      #pragma unroll
      for (int k4 = 0; k4 < 8; ++k4) {
        float4 s  = *(const float4*)&Sg[i8][k4*4];
        float4 cA = *(const float4*)&Cm[jA][k4*4];
        float4 cB = *(const float4*)&Cm[jB][k4*4];
        accA += dot4(s,cA); accB += dot4(s,cB);
      }
      Nn[i8][jA] = accA; Nn[i8][jB] = accB;
      NnT[jA][i8] = accA; NnT[jB][i8] = accB;
      if (tid < DA) {
        float acc = sa[t][tid];
        #pragma unroll
        for (int k = 0; k < DZ; ++k) acc -= Cm[tid][k]*muv[k];
        rv[tid] = acc;
      }
    }
    __syncthreads();

    {
      float acc = 0.0f;
      #pragma unroll
      for (int k4 = 0; k4 < 8; ++k4) {
        float4 c = *(const float4*)&Cm[i16][k4*4];
        float4 n = *(const float4*)&NnT[j16][k4*4];
        acc += dot4(c,n);
      }
      Aug[i16][j16] = acc + ((i16 == j16) ? 0.01f : 0.0f);
      Aug[i16][16 + j16] = (i16 == j16) ? 1.0f : 0.0f;
    }
    __syncthreads();

    if (tid < 64) {
      int lane = tid;
      int r = lane >> 2, cb = lane & 3;
      float v[8];
      #pragma unroll
      for (int j = 0; j < 8; ++j) v[j] = Aug[r][cb*8 + j];
      #pragma unroll
      for (int p = 0; p < DA; ++p) {
        float App = __shfl(v[p & 7], (p << 2) | (p >> 3), 64);
        float f   = __shfl(v[p & 7], (lane & 60) | (p >> 3), 64);
        float prow[8];
        #pragma unroll
        for (int j = 0; j < 8; ++j) prow[j] = __shfl(v[j], (p << 2) | cb, 64);
        float pinv = 1.0f / App;
        if (r == p) {
          #pragma unroll
          for (int j = 0; j < 8; ++j) v[j] *= pinv;
        } else {
          float fp = f * pinv;
          #pragma unroll
          for (int j = 0; j < 8; ++j) v[j] -= fp * prow[j];
        }
      }
      if (cb >= 2) {
        #pragma unroll
        for (int j = 0; j < 8; ++j) Aug[r][cb*8 + j] = v[j];
      }
    }
    __syncthreads();

    {
      float accA = 0.0f, accB = 0.0f;
      #pragma unroll
      for (int k4 = 0; k4 < 4; ++k4) {
        float4 n  = *(const float4*)&Nn[i8][k4*4];
        float4 sA = *(const float4*)&Aug[jA][16 + k4*4];
        float4 sB = *(const float4*)&Aug[jB][16 + k4*4];
        accA += dot4(n,sA); accB += dot4(n,sB);
      }
      Kg[i8][jA] = accA; Kg[i8][jB] = accB;
    }
    __syncthreads();

    if (tid < DZ) {
      float m = muv[tid];
      #pragma unroll
      for (int k = 0; k < DA; ++k) m += Kg[tid][k]*rv[k];
      mun[tid] = m;
      out[((size_t)b*T_LEN + t)*DZ + tid] = m;
    }
    {
      float4 acc = *(const float4*)&Sg[i8][j4];
      #pragma unroll
      for (int k4 = 0; k4 < 4; ++k4) {
        float4 kg = *(const float4*)&Kg[i8][k4*4];
        float4 n0 = *(const float4*)&Nn[j4+0][k4*4];
        float4 n1 = *(const float4*)&Nn[j4+1][k4*4];
        float4 n2 = *(const float4*)&Nn[j4+2][k4*4];
        float4 n3 = *(const float4*)&Nn[j4+3][k4*4];
        acc.x -= dot4(kg,n0); acc.y -= dot4(kg,n1);
        acc.z -= dot4(kg,n2); acc.w -= dot4(kg,n3);
      }
      *(float4*)&Sp2[i8][j4] = acc;
    }
    __syncthreads();

    {
      float4 acc = make_float4(0.f,0.f,0.f,0.f);
      #pragma unroll
      for (int k4 = 0; k4 < 8; ++k4) {
        float4 am = *(const float4*)&Am[i8][k4*4];
        float4 s0 = *(const float4*)&Sp2[j4+0][k4*4];
        float4 s1 = *(const float4*)&Sp2[j4+1][k4*4];
        float4 s2 = *(const float4*)&Sp2[j4+2][k4*4];
        float4 s3 = *(const float4*)&Sp2[j4+3][k4*4];
        acc.x += dot4(am,s0); acc.y += dot4(am,s1);
        acc.z += dot4(am,s2); acc.w += dot4(am,s3);
      }
      *(float4*)&T2m[i8][j4] = acc;
    }
    __syncthreads();

    {
      float4 acc = make_float4(0.f,0.f,0.f,0.f);
      #pragma unroll
      for (int k4 = 0; k4 < 8; ++k4) {
        float4 t2 = *(const float4*)&T2m[i8][k4*4];
        float4 a0 = *(const float4*)&Am[j4+0][k4*4];
        float4 a1 = *(const float4*)&Am[j4+1][k4*4];
        float4 a2 = *(const float4*)&Am[j4+2][k4*4];
        float4 a3 = *(const float4*)&Am[j4+3][k4*4];
        acc.x += dot4(t2,a0); acc.y += dot4(t2,a1);
        acc.z += dot4(t2,a2); acc.w += dot4(t2,a3);
      }
      int d = i8 - j4;
      if (d >= 0 && d < 4) (&acc.x)[d] += 0.01f;
      *(float4*)&Sg[i8][j4] = acc;
    }
    if (tid < DZ) {
      float m = 0.0f;
      #pragma unroll
      for (int k = 0; k < DZ; ++k) m += Am[tid][k]*mun[k];
      muv[tid] = m;
    }
    __syncthreads();
  }
}

extern "C" void kernel_launch(void* const* d_in, const int* in_sizes, int n_in,
                              void* d_out, int out_size, void* d_ws, size_t ws_size,
                              hipStream_t stream) {
  const float* a    = (const float*)d_in[0];
  const float* A    = (const float*)d_in[1];
  const float* C    = (const float*)d_in[2];
  const float* a0   = (const float*)d_in[3];
  const float* Wih0 = (const float*)d_in[4];
  const float* Whh0 = (const float*)d_in[5];
  const float* bih0 = (const float*)d_in[6];
  const float* bhh0 = (const float*)d_in[7];
  const float* Wih1 = (const float*)d_in[8];
  const float* Whh1 = (const float*)d_in[9];
  const float* bih1 = (const float*)d_in[10];
  const float* bhh1 = (const float*)d_in[11];
  const float* Wlin = (const float*)d_in[12];
  const float* blin = (const float*)d_in[13];
  uint32_t* ws = (uint32_t*)d_ws;
  float* alpha = (float*)(ws + 103424);
  float* out = (float*)d_out;

  prep_kernel<<<404, 256, 0, stream>>>(Wih0, Whh0, bih0, bhh0, Wih1, Whh1, bih1, bhh1, ws);
  lstm_kernel<<<256, 512, 0, stream>>>(a, a0, ws, Wlin, blin, alpha);
  kalman_kernel<<<512, 256, 0, stream>>>(a, A, C, alpha, out);
}

// Round 7
// 1481.337 us; speedup vs baseline: 2.3537x; 1.0837x over previous
//
#include <hip/hip_runtime.h>
#include <hip/hip_fp16.h>
#include <cstdint>

#define T_LEN 128
#define DA    16
#define DZ    32
#define HH    128

__device__ __forceinline__ float sigm(float x){ return 1.0f/(1.0f + __expf(-x)); }
__device__ __forceinline__ float tanh_f(float x){ return 1.0f - 2.0f/(__expf(2.0f*x)+1.0f); }
__device__ __forceinline__ float dot4(float4 a, float4 b){ return a.x*b.x + a.y*b.y + a.z*b.z + a.w*b.w; }

typedef _Float16 h2v __attribute__((ext_vector_type(2)));
__device__ __forceinline__ float fdot2(uint32_t w, uint32_t h, float acc){
  union{uint32_t u; h2v v;} a, b; a.u = w; b.u = h;
  return __builtin_amdgcn_fdot2(a.v, b.v, acc, false);
}
__device__ __forceinline__ uint32_t packh2(float x, float y){
  return (uint32_t)__half_as_ushort(__float2half(x)) |
         ((uint32_t)__half_as_ushort(__float2half(y)) << 16);
}

// ws layout (32-bit words):
//   [0,4096)         Wih0h fp16-pairs: word idx (m*512+g)*4+q, m<2, q<4 -> w[g][8m+2q..+1]
//   [4096,36864)     Whh0h: m<16
//   [36864,69632)    Wih1h: m<16
//   [69632,102400)   Whh1h: m<16
//   [102400,102912)  b0 = bih0+bhh0 (f32)
//   [102912,103424)  b1 = bih1+bhh1 (f32)
//   [103424,300032)  alpha (512,128,3) f32

__global__ void prep_kernel(const float* __restrict__ Wih0, const float* __restrict__ Whh0,
                            const float* __restrict__ bih0, const float* __restrict__ bhh0,
                            const float* __restrict__ Wih1, const float* __restrict__ Whh1,
                            const float* __restrict__ bih1, const float* __restrict__ bhh1,
                            uint32_t* __restrict__ ws) {
  int idx = blockIdx.x*256 + threadIdx.x;
  if (idx < 4096) {
    int q = idx & 3, g = (idx >> 2) & 511, m = idx >> 11;
    int k0 = 8*m + 2*q;
    ws[idx] = packh2(Wih0[g*DA + k0], Wih0[g*DA + k0 + 1]);
  } else if (idx < 36864) {
    int f = idx - 4096;
    int q = f & 3, g = (f >> 2) & 511, m = f >> 11;
    int k0 = 8*m + 2*q;
    ws[idx] = packh2(Whh0[g*HH + k0], Whh0[g*HH + k0 + 1]);
  } else if (idx < 69632) {
    int f = idx - 36864;
    int q = f & 3, g = (f >> 2) & 511, m = f >> 11;
    int k0 = 8*m + 2*q;
    ws[idx] = packh2(Wih1[g*HH + k0], Wih1[g*HH + k0 + 1]);
  } else if (idx < 102400) {
    int f = idx - 69632;
    int q = f & 3, g = (f >> 2) & 511, m = f >> 11;
    int k0 = 8*m + 2*q;
    ws[idx] = packh2(Whh1[g*HH + k0], Whh1[g*HH + k0 + 1]);
  } else if (idx < 102912) {
    int j = idx - 102400;
    ((float*)ws)[idx] = bih0[j] + bhh0[j];
  } else if (idx < 103424) {
    int j = idx - 102912;
    ((float*)ws)[idx] = bih1[j] + bhh1[j];
  }
}

// Persistent 2-layer LSTM + softmax head. fp16 weights via v_dot2_f32_f16
// (fp32 accumulate). 256 blocks x 512 threads x 2 rows. (unchanged from r6)
__global__ __launch_bounds__(512, 2) void lstm_kernel(
    const float* __restrict__ a, const float* __restrict__ a0,
    const uint32_t* __restrict__ wsw, const float* __restrict__ Wlin,
    const float* __restrict__ blin, float* __restrict__ alpha_out) {
  const uint4* Wih0p = (const uint4*)(wsw);
  const uint4* Whh0p = (const uint4*)(wsw + 4096);
  const uint4* Wih1p = (const uint4*)(wsw + 36864);
  const uint4* Whh1p = (const uint4*)(wsw + 69632);
  const float* b0v = (const float*)(wsw + 102400);
  const float* b1v = (const float*)(wsw + 102912);

  __shared__ __align__(16) uint32_t sxh[2][T_LEN][8];
  __shared__ __align__(16) uint32_t sh0h[2][64];
  __shared__ __align__(16) uint32_t sh1h[2][64];
  __shared__ float sh1f[2][HH];
  __shared__ float sc0[2][HH], sc1[2][HH];
  __shared__ float gates[2][4*HH];
  __shared__ float sWl[3][HH];
  __shared__ float partial[4][3];

  int tid = threadIdx.x;
  int bb = blockIdx.x * 2;
  for (int i = tid; i < 2*T_LEN*8; i += 512) {
    int r = i / (T_LEN*8), rem = i % (T_LEN*8), t = rem >> 3, p = rem & 7;
    float x0, x1;
    if (t == 0) { x0 = a0[2*p]; x1 = a0[2*p+1]; }
    else {
      const float* src = a + ((size_t)(bb + r)*T_LEN + (t-1))*DA;
      x0 = src[2*p]; x1 = src[2*p+1];
    }
    sxh[r][t][p] = packh2(x0, x1);
  }
  for (int i = tid; i < 3*HH; i += 512) sWl[i/HH][i%HH] = Wlin[i];
  if (tid < 128) { int r = tid>>6, p = tid&63; sh0h[r][p] = 0u; sh1h[r][p] = 0u; }
  if (tid < 256) { int r = tid>>7, j = tid&127; sc0[r][j] = 0.f; sc1[r][j] = 0.f; }
  float bi0 = b0v[tid];
  float bi1 = b1v[tid];
  __syncthreads();

  #pragma unroll 1
  for (int t = 0; t < T_LEN; ++t) {
    float g0 = bi0, g1 = bi0;
    #pragma unroll
    for (int m = 0; m < 2; ++m) {
      uint4 w = Wih0p[m*512 + tid];
      uint4 x0 = *(const uint4*)&sxh[0][t][4*m];
      uint4 x1 = *(const uint4*)&sxh[1][t][4*m];
      g0 = fdot2(w.x, x0.x, g0); g0 = fdot2(w.y, x0.y, g0);
      g0 = fdot2(w.z, x0.z, g0); g0 = fdot2(w.w, x0.w, g0);
      g1 = fdot2(w.x, x1.x, g1); g1 = fdot2(w.y, x1.y, g1);
      g1 = fdot2(w.z, x1.z, g1); g1 = fdot2(w.w, x1.w, g1);
    }
    #pragma unroll 8
    for (int m = 0; m < 16; ++m) {
      uint4 w = Whh0p[m*512 + tid];
      uint4 h0 = *(const uint4*)&sh0h[0][4*m];
      uint4 h1 = *(const uint4*)&sh0h[1][4*m];
      g0 = fdot2(w.x, h0.x, g0); g0 = fdot2(w.y, h0.y, g0);
      g0 = fdot2(w.z, h0.z, g0); g0 = fdot2(w.w, h0.w, g0);
      g1 = fdot2(w.x, h1.x, g1); g1 = fdot2(w.y, h1.y, g1);
      g1 = fdot2(w.z, h1.z, g1); g1 = fdot2(w.w, h1.w, g1);
    }
    gates[0][tid] = g0; gates[1][tid] = g1;
    __syncthreads();
    if (tid < 128) {
      int r = tid>>6, p = tid&63, j0 = 2*p, j1 = j0 + 1;
      float i0 = gates[r][j0],     f0 = gates[r][j0+HH],
            q0 = gates[r][j0+2*HH], o0 = gates[r][j0+3*HH];
      float c0 = sigm(f0)*sc0[r][j0] + sigm(i0)*tanh_f(q0);
      sc0[r][j0] = c0;
      float hv0 = sigm(o0)*tanh_f(c0);
      float i1 = gates[r][j1],     f1 = gates[r][j1+HH],
            q1 = gates[r][j1+2*HH], o1 = gates[r][j1+3*HH];
      float c1 = sigm(f1)*sc0[r][j1] + sigm(i1)*tanh_f(q1);
      sc0[r][j1] = c1;
      float hv1 = sigm(o1)*tanh_f(c1);
      sh0h[r][p] = packh2(hv0, hv1);
    }
    __syncthreads();
    g0 = bi1; g1 = bi1;
    #pragma unroll 8
    for (int m = 0; m < 16; ++m) {
      uint4 w = Wih1p[m*512 + tid];
      uint4 h0 = *(const uint4*)&sh0h[0][4*m];
      uint4 h1 = *(const uint4*)&sh0h[1][4*m];
      g0 = fdot2(w.x, h0.x, g0); g0 = fdot2(w.y, h0.y, g0);
      g0 = fdot2(w.z, h0.z, g0); g0 = fdot2(w.w, h0.w, g0);
      g1 = fdot2(w.x, h1.x, g1); g1 = fdot2(w.y, h1.y, g1);
      g1 = fdot2(w.z, h1.z, g1); g1 = fdot2(w.w, h1.w, g1);
    }
    #pragma unroll 8
    for (int m = 0; m < 16; ++m) {
      uint4 w = Whh1p[m*512 + tid];
      uint4 h0 = *(const uint4*)&sh1h[0][4*m];
      uint4 h1 = *(const uint4*)&sh1h[1][4*m];
      g0 = fdot2(w.x, h0.x, g0); g0 = fdot2(w.y, h0.y, g0);
      g0 = fdot2(w.z, h0.z, g0); g0 = fdot2(w.w, h0.w, g0);
      g1 = fdot2(w.x, h1.x, g1); g1 = fdot2(w.y, h1.y, g1);
      g1 = fdot2(w.z, h1.z, g1); g1 = fdot2(w.w, h1.w, g1);
    }
    gates[0][tid] = g0; gates[1][tid] = g1;
    __syncthreads();
    if (tid < 128) {
      int r = tid>>6, p = tid&63, j0 = 2*p, j1 = j0 + 1;
      float i0 = gates[r][j0],     f0 = gates[r][j0+HH],
            q0 = gates[r][j0+2*HH], o0 = gates[r][j0+3*HH];
      float c0 = sigm(f0)*sc1[r][j0] + sigm(i0)*tanh_f(q0);
      sc1[r][j0] = c0;
      float hv0 = sigm(o0)*tanh_f(c0);
      float i1 = gates[r][j1],     f1 = gates[r][j1+HH],
            q1 = gates[r][j1+2*HH], o1 = gates[r][j1+3*HH];
      float c1 = sigm(f1)*sc1[r][j1] + sigm(i1)*tanh_f(q1);
      sc1[r][j1] = c1;
      float hv1 = sigm(o1)*tanh_f(c1);
      sh1h[r][p] = packh2(hv0, hv1);
      sh1f[r][j0] = hv0; sh1f[r][j1] = hv1;
    }
    __syncthreads();
    if (tid < 256) {
      int wv = tid>>6, lane = tid&63, r = wv>>1, jo = (wv&1)*64;
      float hv = sh1f[r][jo+lane];
      float p0 = hv*sWl[0][jo+lane], p1 = hv*sWl[1][jo+lane], p2 = hv*sWl[2][jo+lane];
      #pragma unroll
      for (int off = 32; off > 0; off >>= 1) {
        p0 += __shfl_down(p0, off); p1 += __shfl_down(p1, off); p2 += __shfl_down(p2, off);
      }
      if (lane == 0) { partial[wv][0]=p0; partial[wv][1]=p1; partial[wv][2]=p2; }
    }
    __syncthreads();
    if (tid < 2) {
      float l0 = partial[2*tid][0]+partial[2*tid+1][0]+blin[0];
      float l1 = partial[2*tid][1]+partial[2*tid+1][1]+blin[1];
      float l2 = partial[2*tid][2]+partial[2*tid+1][2]+blin[2];
      float m = fmaxf(l0, fmaxf(l1, l2));
      float e0=__expf(l0-m), e1=__expf(l1-m), e2=__expf(l2-m);
      float inv = 1.0f/(e0+e1+e2);
      float* dst = alpha_out + (((size_t)(bb+tid))*T_LEN + t)*3;
      dst[0]=e0*inv; dst[1]=e1*inv; dst[2]=e2*inv;
    }
    __syncthreads();
  }
}

// Kalman scan v4: conflict-free k-row matmul formulation for the 32-wide
// phases (B rows read wave-uniform -> 32-way broadcast), A/C global prefetch
// one step ahead, wave-synchronous Gauss-Jordan (unchanged).
__global__ __launch_bounds__(256) void kalman_kernel(
    const float* __restrict__ a, const float* __restrict__ A,
    const float* __restrict__ C, const float* __restrict__ alpha,
    float* __restrict__ out) {
  __shared__ __align__(16) float Sg[DZ][36];
  __shared__ __align__(16) float Am[DZ][36];
  __shared__ __align__(16) float AmT[DZ][36];
  __shared__ __align__(16) float Cm[DA][36];
  __shared__ __align__(16) float Nn[DZ][20];
  __shared__ __align__(16) float NnT[DA][36];
  __shared__ __align__(16) float Aug[DA][36];
  __shared__ __align__(16) float Kg[DZ][20];
  __shared__ __align__(16) float Sp2[DZ][36];
  __shared__ __align__(16) float T2m[DZ][36];
  __shared__ __align__(16) float sa[T_LEN][DA];
  __shared__ float salpha[T_LEN*3];
  __shared__ __align__(16) float muv[DZ], mun[DZ], rv[DA];

  int tid = threadIdx.x;
  int b = blockIdx.x;

  for (int e = tid; e < T_LEN*DA; e += 256) (&sa[0][0])[e] = a[(size_t)b*T_LEN*DA + e];
  for (int e = tid; e < T_LEN*3; e += 256) salpha[e] = alpha[(size_t)b*T_LEN*3 + e];
  for (int e = tid; e < DZ*36; e += 256) (&Sg[0][0])[e] = 0.0f;
  __syncthreads();
  if (tid < DZ) { Sg[tid][tid] = 1.0f; muv[tid] = 0.0f; }

  const int i8 = tid >> 3, jA = tid & 7, jB = jA + 8, j4m = jA * 4; // mix/N/Kg map
  const int i16 = tid >> 4, j16 = tid & 15;                         // S map
  const int iR = tid & 31, j4r = (tid >> 5) * 4;                    // k-row map

  // prefetch A(t=1 slice), C(t=0 slice)
  const float4* A4 = (const float4*)A;
  const float4* C4 = (const float4*)C;
  float4 pA0 = A4[(0*T_LEN + 1)*256 + tid];
  float4 pA1 = A4[(1*T_LEN + 1)*256 + tid];
  float4 pA2 = A4[(2*T_LEN + 1)*256 + tid];
  float4 pC0, pC1, pC2;
  if (tid < 128) {
    pC0 = C4[(0*T_LEN + 0)*128 + tid];
    pC1 = C4[(1*T_LEN + 0)*128 + tid];
    pC2 = C4[(2*T_LEN + 0)*128 + tid];
  }
  __syncthreads();

  #pragma unroll 1
  for (int t = 0; t < T_LEN; ++t) {
    int ta = (t < T_LEN-1) ? t+1 : t;
    float b10 = salpha[ta*3+0], b11 = salpha[ta*3+1], b12 = salpha[ta*3+2];
    float b00 = salpha[t*3+0],  b01 = salpha[t*3+1],  b02 = salpha[t*3+2];

    // ---- MIX from prefetched regs; write Am, AmT, Cm ----
    {
      float4 v;
      v.x = b10*pA0.x + b11*pA1.x + b12*pA2.x;
      v.y = b10*pA0.y + b11*pA1.y + b12*pA2.y;
      v.z = b10*pA0.z + b11*pA1.z + b12*pA2.z;
      v.w = b10*pA0.w + b11*pA1.w + b12*pA2.w;
      *(float4*)&Am[i8][j4m] = v;
      AmT[j4m+0][i8] = v.x; AmT[j4m+1][i8] = v.y;
      AmT[j4m+2][i8] = v.z; AmT[j4m+3][i8] = v.w;
      if (tid < 128) {
        float4 c;
        c.x = b00*pC0.x + b01*pC1.x + b02*pC2.x;
        c.y = b00*pC0.y + b01*pC1.y + b02*pC2.y;
        c.z = b00*pC0.z + b01*pC1.z + b02*pC2.z;
        c.w = b00*pC0.w + b01*pC1.w + b02*pC2.w;
        *(float4*)&Cm[tid>>3][(tid&7)*4] = c;
      }
      // issue prefetch for t+1 (clamped; overlaps this step's compute)
      int tn  = (t+1 < T_LEN) ? t+1 : T_LEN-1;
      int tan = (tn < T_LEN-1) ? tn+1 : tn;
      pA0 = A4[(0*T_LEN + tan)*256 + tid];
      pA1 = A4[(1*T_LEN + tan)*256 + tid];
      pA2 = A4[(2*T_LEN + tan)*256 + tid];
      if (tid < 128) {
        pC0 = C4[(0*T_LEN + tn)*128 + tid];
        pC1 = C4[(1*T_LEN + tn)*128 + tid];
        pC2 = C4[(2*T_LEN + tn)*128 + tid];
      }
    }
    __syncthreads();

    // ---- N = Sg @ Cm^T (Sg symmetric: dot4 of rows); r = a_t - Cm @ mu ----
    {
      float accA = 0.0f, accB = 0.0f;
      #pragma unroll
      for (int k4 = 0; k4 < 8; ++k4) {
        float4 s  = *(const float4*)&Sg[i8][k4*4];
        float4 cA = *(const float4*)&Cm[jA][k4*4];
        float4 cB = *(const float4*)&Cm[jB][k4*4];
        accA += dot4(s,cA); accB += dot4(s,cB);
      }
      Nn[i8][jA] = accA; Nn[i8][jB] = accB;
      NnT[jA][i8] = accA; NnT[jB][i8] = accB;
      if (tid < DA) {
        float acc = sa[t][tid];
        #pragma unroll
        for (int k4 = 0; k4 < 8; ++k4)
          acc -= dot4(*(const float4*)&Cm[tid][k4*4], *(const float4*)&muv[k4*4]);
        rv[tid] = acc;
      }
    }
    __syncthreads();

    // ---- Aug = [S | I], S = Cm @ N + 0.01 I  (dot4 with NnT rows) ----
    {
      float acc = 0.0f;
      #pragma unroll
      for (int k4 = 0; k4 < 8; ++k4) {
        float4 c = *(const float4*)&Cm[i16][k4*4];
        float4 n = *(const float4*)&NnT[j16][k4*4];
        acc += dot4(c,n);
      }
      Aug[i16][j16] = acc + ((i16 == j16) ? 0.01f : 0.0f);
      Aug[i16][16 + j16] = (i16 == j16) ? 1.0f : 0.0f;
    }
    __syncthreads();

    // ---- wave-synchronous Gauss-Jordan (wave 0; S SPD, no pivoting) ----
    if (tid < 64) {
      int lane = tid;
      int r = lane >> 2, cb = lane & 3;
      float v[8];
      #pragma unroll
      for (int j = 0; j < 8; ++j) v[j] = Aug[r][cb*8 + j];
      #pragma unroll
      for (int p = 0; p < DA; ++p) {
        float App = __shfl(v[p & 7], (p << 2) | (p >> 3), 64);
        float f   = __shfl(v[p & 7], (lane & 60) | (p >> 3), 64);
        float prow[8];
        #pragma unroll
        for (int j = 0; j < 8; ++j) prow[j] = __shfl(v[j], (p << 2) | cb, 64);
        float pinv = 1.0f / App;
        if (r == p) {
          #pragma unroll
          for (int j = 0; j < 8; ++j) v[j] *= pinv;
        } else {
          float fp = f * pinv;
          #pragma unroll
          for (int j = 0; j < 8; ++j) v[j] -= fp * prow[j];
        }
      }
      if (cb >= 2) {
        #pragma unroll
        for (int j = 0; j < 8; ++j) Aug[r][cb*8 + j] = v[j];
      }
    }
    __syncthreads();

    // ---- Kg = N @ Sinv (Sinv symmetric: dot4 of rows of right half) ----
    {
      float accA = 0.0f, accB = 0.0f;
      #pragma unroll
      for (int k4 = 0; k4 < 4; ++k4) {
        float4 n  = *(const float4*)&Nn[i8][k4*4];
        float4 sA = *(const float4*)&Aug[jA][16 + k4*4];
        float4 sB = *(const float4*)&Aug[jB][16 + k4*4];
        accA += dot4(n,sA); accB += dot4(n,sB);
      }
      Kg[i8][jA] = accA; Kg[i8][jB] = accB;
    }
    __syncthreads();

    // ---- mu = mu_pred + Kg r (write output); Sp2 = Sg - Kg @ N^T (k-rows) ----
    if (tid < DZ) {
      float m = muv[tid];
      #pragma unroll
      for (int k4 = 0; k4 < 4; ++k4)
        m += dot4(*(const float4*)&Kg[tid][k4*4], *(const float4*)&rv[k4*4]);
      mun[tid] = m;
      out[((size_t)b*T_LEN + t)*DZ + tid] = m;
    }
    {
      float4 acc = *(const float4*)&Sg[iR][j4r];
      #pragma unroll
      for (int k4 = 0; k4 < 4; ++k4) {
        float4 kv = *(const float4*)&Kg[iR][k4*4];
        float4 n0 = *(const float4*)&NnT[4*k4+0][j4r];
        float4 n1 = *(const float4*)&NnT[4*k4+1][j4r];
        float4 n2 = *(const float4*)&NnT[4*k4+2][j4r];
        float4 n3 = *(const float4*)&NnT[4*k4+3][j4r];
        acc.x -= kv.x*n0.x + kv.y*n1.x + kv.z*n2.x + kv.w*n3.x;
        acc.y -= kv.x*n0.y + kv.y*n1.y + kv.z*n2.y + kv.w*n3.y;
        acc.z -= kv.x*n0.z + kv.y*n1.z + kv.z*n2.z + kv.w*n3.z;
        acc.w -= kv.x*n0.w + kv.y*n1.w + kv.z*n2.w + kv.w*n3.w;
      }
      *(float4*)&Sp2[iR][j4r] = acc;
    }
    __syncthreads();

    // ---- T2 = Am @ Sp2 (k-rows: B rows wave-uniform) ----
    {
      float4 acc = make_float4(0.f,0.f,0.f,0.f);
      #pragma unroll
      for (int k4 = 0; k4 < 8; ++k4) {
        float4 av = *(const float4*)&Am[iR][k4*4];
        float4 b0 = *(const float4*)&Sp2[4*k4+0][j4r];
        float4 b1 = *(const float4*)&Sp2[4*k4+1][j4r];
        float4 b2 = *(const float4*)&Sp2[4*k4+2][j4r];
        float4 b3 = *(const float4*)&Sp2[4*k4+3][j4r];
        acc.x += av.x*b0.x + av.y*b1.x + av.z*b2.x + av.w*b3.x;
        acc.y += av.x*b0.y + av.y*b1.y + av.z*b2.y + av.w*b3.y;
        acc.z += av.x*b0.z + av.y*b1.z + av.z*b2.z + av.w*b3.z;
        acc.w += av.x*b0.w + av.y*b1.w + av.z*b2.w + av.w*b3.w;
      }
      *(float4*)&T2m[iR][j4r] = acc;
    }
    __syncthreads();

    // ---- Sg_next = T2 @ Am^T + 0.01 I (k-rows with AmT); mu_next = Am @ mu ----
    {
      float4 acc = make_float4(0.f,0.f,0.f,0.f);
      #pragma unroll
      for (int k4 = 0; k4 < 8; ++k4) {
        float4 tv = *(const float4*)&T2m[iR][k4*4];
        float4 b0 = *(const float4*)&AmT[4*k4+0][j4r];
        float4 b1 = *(const float4*)&AmT[4*k4+1][j4r];
        float4 b2 = *(const float4*)&AmT[4*k4+2][j4r];
        float4 b3 = *(const float4*)&AmT[4*k4+3][j4r];
        acc.x += tv.x*b0.x + tv.y*b1.x + tv.z*b2.x + tv.w*b3.x;
        acc.y += tv.x*b0.y + tv.y*b1.y + tv.z*b2.y + tv.w*b3.y;
        acc.z += tv.x*b0.z + tv.y*b1.z + tv.z*b2.z + tv.w*b3.z;
        acc.w += tv.x*b0.w + tv.y*b1.w + tv.z*b2.w + tv.w*b3.w;
      }
      int d = iR - j4r;
      if (d >= 0 && d < 4) (&acc.x)[d] += 0.01f;
      *(float4*)&Sg[iR][j4r] = acc;
    }
    if (tid < DZ) {
      float m = 0.0f;
      #pragma unroll
      for (int k4 = 0; k4 < 8; ++k4)
        m += dot4(*(const float4*)&Am[tid][k4*4], *(const float4*)&mun[k4*4]);
      muv[tid] = m;
    }
    __syncthreads();
  }
}

extern "C" void kernel_launch(void* const* d_in, const int* in_sizes, int n_in,
                              void* d_out, int out_size, void* d_ws, size_t ws_size,
                              hipStream_t stream) {
  const float* a    = (const float*)d_in[0];
  const float* A    = (const float*)d_in[1];
  const float* C    = (const float*)d_in[2];
  const float* a0   = (const float*)d_in[3];
  const float* Wih0 = (const float*)d_in[4];
  const float* Whh0 = (const float*)d_in[5];
  const float* bih0 = (const float*)d_in[6];
  const float* bhh0 = (const float*)d_in[7];
  const float* Wih1 = (const float*)d_in[8];
  const float* Whh1 = (const float*)d_in[9];
  const float* bih1 = (const float*)d_in[10];
  const float* bhh1 = (const float*)d_in[11];
  const float* Wlin = (const float*)d_in[12];
  const float* blin = (const float*)d_in[13];
  uint32_t* ws = (uint32_t*)d_ws;
  float* alpha = (float*)(ws + 103424);
  float* out = (float*)d_out;

  prep_kernel<<<404, 256, 0, stream>>>(Wih0, Whh0, bih0, bhh0, Wih1, Whh1, bih1, bhh1, ws);
  lstm_kernel<<<256, 512, 0, stream>>>(a, a0, ws, Wlin, blin, alpha);
  kalman_kernel<<<512, 256, 0, stream>>>(a, A, C, alpha, out);
}

// Round 8
// 1406.583 us; speedup vs baseline: 2.4788x; 1.0531x over previous
//
#include <hip/hip_runtime.h>
#include <hip/hip_fp16.h>
#include <cstdint>

#define T_LEN 128
#define DA    16
#define DZ    32
#define HH    128

__device__ __forceinline__ float sigm(float x){ return 1.0f/(1.0f + __expf(-x)); }
__device__ __forceinline__ float tanh_f(float x){ return 1.0f - 2.0f/(__expf(2.0f*x)+1.0f); }
__device__ __forceinline__ float dot4(float4 a, float4 b){ return a.x*b.x + a.y*b.y + a.z*b.z + a.w*b.w; }

typedef _Float16 h2v __attribute__((ext_vector_type(2)));
__device__ __forceinline__ float fdot2(uint32_t w, uint32_t h, float acc){
  union{uint32_t u; h2v v;} a, b; a.u = w; b.u = h;
  return __builtin_amdgcn_fdot2(a.v, b.v, acc, false);
}
__device__ __forceinline__ uint32_t packh2(float x, float y){
  return (uint32_t)__half_as_ushort(__float2half(x)) |
         ((uint32_t)__half_as_ushort(__float2half(y)) << 16);
}

// ws layout (32-bit words):
//   [0,4096)         Wih0h fp16-pairs: word idx (m*512+g)*4+q, m<2, q<4 -> w[g][8m+2q..+1]
//   [4096,36864)     Whh0h: m<16
//   [36864,69632)    Wih1h: m<16
//   [69632,102400)   Whh1h: m<16
//   [102400,102912)  b0 = bih0+bhh0 (f32)
//   [102912,103424)  b1 = bih1+bhh1 (f32)
//   [103424,300032)  alpha (512,128,3) f32

__global__ void prep_kernel(const float* __restrict__ Wih0, const float* __restrict__ Whh0,
                            const float* __restrict__ bih0, const float* __restrict__ bhh0,
                            const float* __restrict__ Wih1, const float* __restrict__ Whh1,
                            const float* __restrict__ bih1, const float* __restrict__ bhh1,
                            uint32_t* __restrict__ ws) {
  int idx = blockIdx.x*256 + threadIdx.x;
  if (idx < 4096) {
    int q = idx & 3, g = (idx >> 2) & 511, m = idx >> 11;
    int k0 = 8*m + 2*q;
    ws[idx] = packh2(Wih0[g*DA + k0], Wih0[g*DA + k0 + 1]);
  } else if (idx < 36864) {
    int f = idx - 4096;
    int q = f & 3, g = (f >> 2) & 511, m = f >> 11;
    int k0 = 8*m + 2*q;
    ws[idx] = packh2(Whh0[g*HH + k0], Whh0[g*HH + k0 + 1]);
  } else if (idx < 69632) {
    int f = idx - 36864;
    int q = f & 3, g = (f >> 2) & 511, m = f >> 11;
    int k0 = 8*m + 2*q;
    ws[idx] = packh2(Wih1[g*HH + k0], Wih1[g*HH + k0 + 1]);
  } else if (idx < 102400) {
    int f = idx - 69632;
    int q = f & 3, g = (f >> 2) & 511, m = f >> 11;
    int k0 = 8*m + 2*q;
    ws[idx] = packh2(Whh1[g*HH + k0], Whh1[g*HH + k0 + 1]);
  } else if (idx < 102912) {
    int j = idx - 102400;
    ((float*)ws)[idx] = bih0[j] + bhh0[j];
  } else if (idx < 103424) {
    int j = idx - 102912;
    ((float*)ws)[idx] = bih1[j] + bhh1[j];
  }
}

// Persistent 2-layer LSTM v7: REGISTER-RESIDENT WEIGHTS. One block = one batch
// row; thread g holds its full weight rows for all 4 matrices in VGPRs
// (2+16+16+16 uint4 = 200 VGPR of fp16 pairs) -> zero weight loads inside the
// 128-step loop (was 400 KB/step/CU from L2 = the round-7 bottleneck).
// 4 barriers/step; softmax head is an in-wave shuffle reduce in wave 0.
// Hazard analysis for dropped 5th barrier: head reads sh1f/sWl only; the next
// writers of sh1f/sh1h (act1 of t+1, wave 0 itself) and of gates (L0g of t+1,
// after B4(t)) are ordered behind the existing barriers.
__global__ __launch_bounds__(512, 2) void lstm_kernel(
    const float* __restrict__ a, const float* __restrict__ a0,
    const uint32_t* __restrict__ wsw, const float* __restrict__ Wlin,
    const float* __restrict__ blin, float* __restrict__ alpha_out) {
  const uint4* Wih0p = (const uint4*)(wsw);
  const uint4* Whh0p = (const uint4*)(wsw + 4096);
  const uint4* Wih1p = (const uint4*)(wsw + 36864);
  const uint4* Whh1p = (const uint4*)(wsw + 69632);
  const float* b0v = (const float*)(wsw + 102400);
  const float* b1v = (const float*)(wsw + 102912);

  __shared__ __align__(16) uint32_t sxh[T_LEN][8];   // x packed half2 (this row)
  __shared__ __align__(16) uint32_t sh0h[64];        // h0 packed half2
  __shared__ __align__(16) uint32_t sh1h[64];        // h1 packed half2
  __shared__ float gates[4*HH];
  __shared__ float sh1f[HH];
  __shared__ float sWl[3][HH];

  int tid = threadIdx.x;
  int b = blockIdx.x;

  // ---- one-time: weights into registers (L2-broadcast, ~6 us fleet-wide) ----
  uint4 wi0[2], wh0[16], wi1[16], wh1[16];
  #pragma unroll
  for (int m = 0; m < 2; ++m)  wi0[m] = Wih0p[m*512 + tid];
  #pragma unroll
  for (int m = 0; m < 16; ++m) wh0[m] = Whh0p[m*512 + tid];
  #pragma unroll
  for (int m = 0; m < 16; ++m) wi1[m] = Wih1p[m*512 + tid];
  #pragma unroll
  for (int m = 0; m < 16; ++m) wh1[m] = Whh1p[m*512 + tid];
  float bi0 = b0v[tid], bi1 = b1v[tid];

  for (int i = tid; i < T_LEN*8; i += 512) {
    int t = i >> 3, p = i & 7;
    float x0, x1;
    if (t == 0) { x0 = a0[2*p]; x1 = a0[2*p+1]; }
    else {
      const float* src = a + ((size_t)b*T_LEN + (t-1))*DA;
      x0 = src[2*p]; x1 = src[2*p+1];
    }
    sxh[t][p] = packh2(x0, x1);
  }
  for (int i = tid; i < 3*HH; i += 512) sWl[i/HH][i%HH] = Wlin[i];
  if (tid < 64) { sh0h[tid] = 0u; sh1h[tid] = 0u; }
  // cell states live in the activation threads' registers (tid<64: cells 2tid,2tid+1)
  float c00 = 0.f, c01 = 0.f, c10 = 0.f, c11 = 0.f;
  __syncthreads();

  #pragma unroll 1
  for (int t = 0; t < T_LEN; ++t) {
    // ---- layer 0 gates: g = tid ----
    float g = bi0;
    {
      uint4 x0 = *(const uint4*)&sxh[t][0];
      uint4 x1 = *(const uint4*)&sxh[t][4];
      g = fdot2(wi0[0].x, x0.x, g); g = fdot2(wi0[0].y, x0.y, g);
      g = fdot2(wi0[0].z, x0.z, g); g = fdot2(wi0[0].w, x0.w, g);
      g = fdot2(wi0[1].x, x1.x, g); g = fdot2(wi0[1].y, x1.y, g);
      g = fdot2(wi0[1].z, x1.z, g); g = fdot2(wi0[1].w, x1.w, g);
    }
    #pragma unroll
    for (int m = 0; m < 16; ++m) {
      uint4 h = *(const uint4*)&sh0h[4*m];
      g = fdot2(wh0[m].x, h.x, g); g = fdot2(wh0[m].y, h.y, g);
      g = fdot2(wh0[m].z, h.z, g); g = fdot2(wh0[m].w, h.w, g);
    }
    gates[tid] = g;
    __syncthreads();                                   // B1
    if (tid < 64) {
      int j0 = 2*tid, j1 = j0 + 1;
      float i0 = gates[j0],      f0 = gates[j0+HH],
            q0 = gates[j0+2*HH], o0 = gates[j0+3*HH];
      c00 = sigm(f0)*c00 + sigm(i0)*tanh_f(q0);
      float hv0 = sigm(o0)*tanh_f(c00);
      float i1 = gates[j1],      f1 = gates[j1+HH],
            q1 = gates[j1+2*HH], o1 = gates[j1+3*HH];
      c01 = sigm(f1)*c01 + sigm(i1)*tanh_f(q1);
      float hv1 = sigm(o1)*tanh_f(c01);
      sh0h[tid] = packh2(hv0, hv1);
    }
    __syncthreads();                                   // B2
    // ---- layer 1 gates ----
    g = bi1;
    #pragma unroll
    for (int m = 0; m < 16; ++m) {
      uint4 h = *(const uint4*)&sh0h[4*m];
      g = fdot2(wi1[m].x, h.x, g); g = fdot2(wi1[m].y, h.y, g);
      g = fdot2(wi1[m].z, h.z, g); g = fdot2(wi1[m].w, h.w, g);
    }
    #pragma unroll
    for (int m = 0; m < 16; ++m) {
      uint4 h = *(const uint4*)&sh1h[4*m];
      g = fdot2(wh1[m].x, h.x, g); g = fdot2(wh1[m].y, h.y, g);
      g = fdot2(wh1[m].z, h.z, g); g = fdot2(wh1[m].w, h.w, g);
    }
    gates[tid] = g;
    __syncthreads();                                   // B3
    if (tid < 64) {
      int j0 = 2*tid, j1 = j0 + 1;
      float i0 = gates[j0],      f0 = gates[j0+HH],
            q0 = gates[j0+2*HH], o0 = gates[j0+3*HH];
      c10 = sigm(f0)*c10 + sigm(i0)*tanh_f(q0);
      float hv0 = sigm(o0)*tanh_f(c10);
      float i1 = gates[j1],      f1 = gates[j1+HH],
            q1 = gates[j1+2*HH], o1 = gates[j1+3*HH];
      c11 = sigm(f1)*c11 + sigm(i1)*tanh_f(q1);
      float hv1 = sigm(o1)*tanh_f(c11);
      sh1h[tid] = packh2(hv0, hv1);
      sh1f[j0] = hv0; sh1f[j1] = hv1;
    }
    __syncthreads();                                   // B4
    // ---- head: softmax(h1 @ Wlin^T + blin), wave 0 only, in-wave reduce ----
    if (tid < 64) {
      float hA = sh1f[tid], hB = sh1f[64+tid];
      float p0 = hA*sWl[0][tid] + hB*sWl[0][64+tid];
      float p1 = hA*sWl[1][tid] + hB*sWl[1][64+tid];
      float p2 = hA*sWl[2][tid] + hB*sWl[2][64+tid];
      #pragma unroll
      for (int off = 32; off > 0; off >>= 1) {
        p0 += __shfl_down(p0, off); p1 += __shfl_down(p1, off); p2 += __shfl_down(p2, off);
      }
      if (tid == 0) {
        float l0 = p0 + blin[0], l1 = p1 + blin[1], l2 = p2 + blin[2];
        float mx = fmaxf(l0, fmaxf(l1, l2));
        float e0=__expf(l0-mx), e1=__expf(l1-mx), e2=__expf(l2-mx);
        float inv = 1.0f/(e0+e1+e2);
        float* dst = alpha_out + ((size_t)b*T_LEN + t)*3;
        dst[0]=e0*inv; dst[1]=e1*inv; dst[2]=e2*inv;
      }
    }
    // no barrier needed: next writers of sh1f/sh1h/gates are ordered behind B1..B4 of t+1
  }
}

// Kalman scan v4 (unchanged from round 7): conflict-free k-row matmuls,
// register prefetch of A/C, wave-synchronous Gauss-Jordan.
__global__ __launch_bounds__(256) void kalman_kernel(
    const float* __restrict__ a, const float* __restrict__ A,
    const float* __restrict__ C, const float* __restrict__ alpha,
    float* __restrict__ out) {
  __shared__ __align__(16) float Sg[DZ][36];
  __shared__ __align__(16) float Am[DZ][36];
  __shared__ __align__(16) float AmT[DZ][36];
  __shared__ __align__(16) float Cm[DA][36];
  __shared__ __align__(16) float Nn[DZ][20];
  __shared__ __align__(16) float NnT[DA][36];
  __shared__ __align__(16) float Aug[DA][36];
  __shared__ __align__(16) float Kg[DZ][20];
  __shared__ __align__(16) float Sp2[DZ][36];
  __shared__ __align__(16) float T2m[DZ][36];
  __shared__ __align__(16) float sa[T_LEN][DA];
  __shared__ float salpha[T_LEN*3];
  __shared__ __align__(16) float muv[DZ], mun[DZ], rv[DA];

  int tid = threadIdx.x;
  int b = blockIdx.x;

  for (int e = tid; e < T_LEN*DA; e += 256) (&sa[0][0])[e] = a[(size_t)b*T_LEN*DA + e];
  for (int e = tid; e < T_LEN*3; e += 256) salpha[e] = alpha[(size_t)b*T_LEN*3 + e];
  for (int e = tid; e < DZ*36; e += 256) (&Sg[0][0])[e] = 0.0f;
  __syncthreads();
  if (tid < DZ) { Sg[tid][tid] = 1.0f; muv[tid] = 0.0f; }

  const int i8 = tid >> 3, jA = tid & 7, jB = jA + 8, j4m = jA * 4;
  const int i16 = tid >> 4, j16 = tid & 15;
  const int iR = tid & 31, j4r = (tid >> 5) * 4;

  const float4* A4 = (const float4*)A;
  const float4* C4 = (const float4*)C;
  float4 pA0 = A4[(0*T_LEN + 1)*256 + tid];
  float4 pA1 = A4[(1*T_LEN + 1)*256 + tid];
  float4 pA2 = A4[(2*T_LEN + 1)*256 + tid];
  float4 pC0, pC1, pC2;
  if (tid < 128) {
    pC0 = C4[(0*T_LEN + 0)*128 + tid];
    pC1 = C4[(1*T_LEN + 0)*128 + tid];
    pC2 = C4[(2*T_LEN + 0)*128 + tid];
  }
  __syncthreads();

  #pragma unroll 1
  for (int t = 0; t < T_LEN; ++t) {
    int ta = (t < T_LEN-1) ? t+1 : t;
    float b10 = salpha[ta*3+0], b11 = salpha[ta*3+1], b12 = salpha[ta*3+2];
    float b00 = salpha[t*3+0],  b01 = salpha[t*3+1],  b02 = salpha[t*3+2];

    {
      float4 v;
      v.x = b10*pA0.x + b11*pA1.x + b12*pA2.x;
      v.y = b10*pA0.y + b11*pA1.y + b12*pA2.y;
      v.z = b10*pA0.z + b11*pA1.z + b12*pA2.z;
      v.w = b10*pA0.w + b11*pA1.w + b12*pA2.w;
      *(float4*)&Am[i8][j4m] = v;
      AmT[j4m+0][i8] = v.x; AmT[j4m+1][i8] = v.y;
      AmT[j4m+2][i8] = v.z; AmT[j4m+3][i8] = v.w;
      if (tid < 128) {
        float4 c;
        c.x = b00*pC0.x + b01*pC1.x + b02*pC2.x;
        c.y = b00*pC0.y + b01*pC1.y + b02*pC2.y;
        c.z = b00*pC0.z + b01*pC1.z + b02*pC2.z;
        c.w = b00*pC0.w + b01*pC1.w + b02*pC2.w;
        *(float4*)&Cm[tid>>3][(tid&7)*4] = c;
      }
      int tn  = (t+1 < T_LEN) ? t+1 : T_LEN-1;
      int tan = (tn < T_LEN-1) ? tn+1 : tn;
      pA0 = A4[(0*T_LEN + tan)*256 + tid];
      pA1 = A4[(1*T_LEN + tan)*256 + tid];
      pA2 = A4[(2*T_LEN + tan)*256 + tid];
      if (tid < 128) {
        pC0 = C4[(0*T_LEN + tn)*128 + tid];
        pC1 = C4[(1*T_LEN + tn)*128 + tid];
        pC2 = C4[(2*T_LEN + tn)*128 + tid];
      }
    }
    __syncthreads();

    {
      float accA = 0.0f, accB = 0.0f;
      #pragma unroll
      for (int k4 = 0; k4 < 8; ++k4) {
        float4 s  = *(const float4*)&Sg[i8][k4*4];
        float4 cA = *(const float4*)&Cm[jA][k4*4];
        float4 cB = *(const float4*)&Cm[jB][k4*4];
        accA += dot4(s,cA); accB += dot4(s,cB);
      }
      Nn[i8][jA] = accA; Nn[i8][jB] = accB;
      NnT[jA][i8] = accA; NnT[jB][i8] = accB;
      if (tid < DA) {
        float acc = sa[t][tid];
        #pragma unroll
        for (int k4 = 0; k4 < 8; ++k4)
          acc -= dot4(*(const float4*)&Cm[tid][k4*4], *(const float4*)&muv[k4*4]);
        rv[tid] = acc;
      }
    }
    __syncthreads();

    {
      float acc = 0.0f;
      #pragma unroll
      for (int k4 = 0; k4 < 8; ++k4) {
        float4 c = *(const float4*)&Cm[i16][k4*4];
        float4 n = *(const float4*)&NnT[j16][k4*4];
        acc += dot4(c,n);
      }
      Aug[i16][j16] = acc + ((i16 == j16) ? 0.01f : 0.0f);
      Aug[i16][16 + j16] = (i16 == j16) ? 1.0f : 0.0f;
    }
    __syncthreads();

    if (tid < 64) {
      int lane = tid;
      int r = lane >> 2, cb = lane & 3;
      float v[8];
      #pragma unroll
      for (int j = 0; j < 8; ++j) v[j] = Aug[r][cb*8 + j];
      #pragma unroll
      for (int p = 0; p < DA; ++p) {
        float App = __shfl(v[p & 7], (p << 2) | (p >> 3), 64);
        float f   = __shfl(v[p & 7], (lane & 60) | (p >> 3), 64);
        float prow[8];
        #pragma unroll
        for (int j = 0; j < 8; ++j) prow[j] = __shfl(v[j], (p << 2) | cb, 64);
        float pinv = 1.0f / App;
        if (r == p) {
          #pragma unroll
          for (int j = 0; j < 8; ++j) v[j] *= pinv;
        } else {
          float fp = f * pinv;
          #pragma unroll
          for (int j = 0; j < 8; ++j) v[j] -= fp * prow[j];
        }
      }
      if (cb >= 2) {
        #pragma unroll
        for (int j = 0; j < 8; ++j) Aug[r][cb*8 + j] = v[j];
      }
    }
    __syncthreads();

    {
      float accA = 0.0f, accB = 0.0f;
      #pragma unroll
      for (int k4 = 0; k4 < 4; ++k4) {
        float4 n  = *(const float4*)&Nn[i8][k4*4];
        float4 sA = *(const float4*)&Aug[jA][16 + k4*4];
        float4 sB = *(const float4*)&Aug[jB][16 + k4*4];
        accA += dot4(n,sA); accB += dot4(n,sB);
      }
      Kg[i8][jA] = accA; Kg[i8][jB] = accB;
    }
    __syncthreads();

    if (tid < DZ) {
      float m = muv[tid];
      #pragma unroll
      for (int k4 = 0; k4 < 4; ++k4)
        m += dot4(*(const float4*)&Kg[tid][k4*4], *(const float4*)&rv[k4*4]);
      mun[tid] = m;
      out[((size_t)b*T_LEN + t)*DZ + tid] = m;
    }
    {
      float4 acc = *(const float4*)&Sg[iR][j4r];
      #pragma unroll
      for (int k4 = 0; k4 < 4; ++k4) {
        float4 kv = *(const float4*)&Kg[iR][k4*4];
        float4 n0 = *(const float4*)&NnT[4*k4+0][j4r];
        float4 n1 = *(const float4*)&NnT[4*k4+1][j4r];
        float4 n2 = *(const float4*)&NnT[4*k4+2][j4r];
        float4 n3 = *(const float4*)&NnT[4*k4+3][j4r];
        acc.x -= kv.x*n0.x + kv.y*n1.x + kv.z*n2.x + kv.w*n3.x;
        acc.y -= kv.x*n0.y + kv.y*n1.y + kv.z*n2.y + kv.w*n3.y;
        acc.z -= kv.x*n0.z + kv.y*n1.z + kv.z*n2.z + kv.w*n3.z;
        acc.w -= kv.x*n0.w + kv.y*n1.w + kv.z*n2.w + kv.w*n3.w;
      }
      *(float4*)&Sp2[iR][j4r] = acc;
    }
    __syncthreads();

    {
      float4 acc = make_float4(0.f,0.f,0.f,0.f);
      #pragma unroll
      for (int k4 = 0; k4 < 8; ++k4) {
        float4 av = *(const float4*)&Am[iR][k4*4];
        float4 b0 = *(const float4*)&Sp2[4*k4+0][j4r];
        float4 b1 = *(const float4*)&Sp2[4*k4+1][j4r];
        float4 b2 = *(const float4*)&Sp2[4*k4+2][j4r];
        float4 b3 = *(const float4*)&Sp2[4*k4+3][j4r];
        acc.x += av.x*b0.x + av.y*b1.x + av.z*b2.x + av.w*b3.x;
        acc.y += av.x*b0.y + av.y*b1.y + av.z*b2.y + av.w*b3.y;
        acc.z += av.x*b0.z + av.y*b1.z + av.z*b2.z + av.w*b3.z;
        acc.w += av.x*b0.w + av.y*b1.w + av.z*b2.w + av.w*b3.w;
      }
      *(float4*)&T2m[iR][j4r] = acc;
    }
    __syncthreads();

    {
      float4 acc = make_float4(0.f,0.f,0.f,0.f);
      #pragma unroll
      for (int k4 = 0; k4 < 8; ++k4) {
        float4 tv = *(const float4*)&T2m[iR][k4*4];
        float4 b0 = *(const float4*)&AmT[4*k4+0][j4r];
        float4 b1 = *(const float4*)&AmT[4*k4+1][j4r];
        float4 b2 = *(const float4*)&AmT[4*k4+2][j4r];
        float4 b3 = *(const float4*)&AmT[4*k4+3][j4r];
        acc.x += tv.x*b0.x + tv.y*b1.x + tv.z*b2.x + tv.w*b3.x;
        acc.y += tv.x*b0.y + tv.y*b1.y + tv.z*b2.y + tv.w*b3.y;
        acc.z += tv.x*b0.z + tv.y*b1.z + tv.z*b2.z + tv.w*b3.z;
        acc.w += tv.x*b0.w + tv.y*b1.w + tv.z*b2.w + tv.w*b3.w;
      }
      int d = iR - j4r;
      if (d >= 0 && d < 4) (&acc.x)[d] += 0.01f;
      *(float4*)&Sg[iR][j4r] = acc;
    }
    if (tid < DZ) {
      float m = 0.0f;
      #pragma unroll
      for (int k4 = 0; k4 < 8; ++k4)
        m += dot4(*(const float4*)&Am[tid][k4*4], *(const float4*)&mun[k4*4]);
      muv[tid] = m;
    }
    __syncthreads();
  }
}

extern "C" void kernel_launch(void* const* d_in, const int* in_sizes, int n_in,
                              void* d_out, int out_size, void* d_ws, size_t ws_size,
                              hipStream_t stream) {
  const float* a    = (const float*)d_in[0];
  const float* A    = (const float*)d_in[1];
  const float* C    = (const float*)d_in[2];
  const float* a0   = (const float*)d_in[3];
  const float* Wih0 = (const float*)d_in[4];
  const float* Whh0 = (const float*)d_in[5];
  const float* bih0 = (const float*)d_in[6];
  const float* bhh0 = (const float*)d_in[7];
  const float* Wih1 = (const float*)d_in[8];
  const float* Whh1 = (const float*)d_in[9];
  const float* bih1 = (const float*)d_in[10];
  const float* bhh1 = (const float*)d_in[11];
  const float* Wlin = (const float*)d_in[12];
  const float* blin = (const float*)d_in[13];
  uint32_t* ws = (uint32_t*)d_ws;
  float* alpha = (float*)(ws + 103424);
  float* out = (float*)d_out;

  prep_kernel<<<404, 256, 0, stream>>>(Wih0, Whh0, bih0, bhh0, Wih1, Whh1, bih1, bhh1, ws);
  lstm_kernel<<<512, 512, 0, stream>>>(a, a0, ws, Wlin, blin, alpha);
  kalman_kernel<<<512, 256, 0, stream>>>(a, A, C, alpha, out);
}